// Round 1
// baseline (1637.068 us; speedup 1.0000x reference)
//
#include <hip/hip_runtime.h>
#include <hip/hip_bf16.h>
#include <math.h>

// Problem constants (from reference)
#define N_ 20000
#define E_ 160000
#define DIM_IN_ 6
#define L_ 128
#define A_ 8
#define NL_ 4
#define EIN_ 273          // 2*L + 2*A + 1
#define MAX_R_ 50.0f

#define BE 32             // edges per block in edge MLP
#define SLD 276           // padded LDS stride for m_in (mult of 4 for float4 stores)

// ---------------- setup kernels ----------------

__global__ void k_init_y(const float* __restrict__ x, const float* __restrict__ W,
                         float* __restrict__ y, float* __restrict__ y_old) {
    int tid = blockIdx.x * blockDim.x + threadIdx.x;   // N_*L_ threads
    if (tid >= N_ * L_) return;
    int n = tid >> 7, l = tid & 127;
    float a = 0.f;
#pragma unroll
    for (int d = 0; d < DIM_IN_; ++d) a = fmaf(x[n * DIM_IN_ + d], W[l * DIM_IN_ + d], a);
    y[tid] = a;
    y_old[tid] = a;
}

__global__ void k_attr(const int* __restrict__ node_attr, const float* __restrict__ embed,
                       float* __restrict__ attr_e) {
    int tid = blockIdx.x * blockDim.x + threadIdx.x;   // N_*A_ threads
    if (tid >= N_ * A_) return;
    int n = tid >> 3, a = tid & 7;
    attr_e[tid] = embed[node_attr[n] * A_ + a];
}

// x_out[n][d] = sum_l y[n][l] * W[l][d]
__global__ void k_x(const float* __restrict__ y, const float* __restrict__ W,
                    float* __restrict__ x_out) {
    int tid = blockIdx.x * blockDim.x + threadIdx.x;   // N_*6 threads
    if (tid >= N_ * DIM_IN_) return;
    int n = tid / DIM_IN_, d = tid % DIM_IN_;
    float a = 0.f;
    for (int l = 0; l < L_; ++l) a = fmaf(y[(size_t)n * L_ + l], W[l * DIM_IN_ + d], a);
    x_out[tid] = a;
}

__global__ void k_edge_w(const float* __restrict__ xp, const int* __restrict__ esrc,
                         const int* __restrict__ edst, float* __restrict__ w_e) {
    int e = blockIdx.x * blockDim.x + threadIdx.x;
    if (e >= E_) return;
    int s = esrc[e], d = edst[e];
    float dx = xp[s * DIM_IN_ + 0] - xp[d * DIM_IN_ + 0];
    float dy = xp[s * DIM_IN_ + 1] - xp[d * DIM_IN_ + 1];
    float dz = xp[s * DIM_IN_ + 2] - xp[d * DIM_IN_ + 2];
    float len = sqrtf(dx * dx + dy * dy + dz * dz);
    float u = 2.f * (len / MAX_R_ - 1.f);
    float cv;
    if (u > 0.f)       cv = 0.f;
    else if (u < -1.f) cv = 1.f;
    else               cv = 0.5f * (1.f - cosf(3.14159265358979323846f * u));
    w_e[e] = cv / len;
}

__global__ void k_scalars(float* __restrict__ tail) {
    int j = threadIdx.x;
    if (j < 4) tail[j] = (j < 2) ? -1.0f : 0.0f;
}

// ---------------- edge MLP (fused 2-layer MLP + atomic scatter) ----------------
// m_in = [y[src](128) | y[dst](128) | attr[src](8) | attr[dst](8) | w(1)]  (273)
// h = silu(m_in @ w1 + b1); m = h @ w2 + b2; agg[dst] += m  (atomic)
__global__ __launch_bounds__(256) void k_edge_mlp(
    const float* __restrict__ y, const float* __restrict__ attr_e,
    const float* __restrict__ w_e, const int* __restrict__ esrc,
    const int* __restrict__ edst,
    const float* __restrict__ w1, const float* __restrict__ b1,
    const float* __restrict__ w2, const float* __restrict__ b2,
    float* __restrict__ agg) {
    __shared__ float s_in[BE * SLD];    // 35328 B
    __shared__ float s_h[BE * L_];      // 16384 B
    __shared__ int   s_src[BE], s_dst[BE];

    const int t  = threadIdx.x;
    const int e0 = blockIdx.x * BE;
    if (t < BE) { s_src[t] = esrc[e0 + t]; s_dst[t] = edst[e0 + t]; }
    __syncthreads();

    // stage y[src], y[dst] rows (float4, coalesced)
    for (int i = t; i < BE * 32; i += 256) {
        int e = i >> 5, l4 = (i & 31) * 4;
        float4 vs = *(const float4*)&y[(size_t)s_src[e] * L_ + l4];
        float4 vd = *(const float4*)&y[(size_t)s_dst[e] * L_ + l4];
        *(float4*)&s_in[e * SLD + l4] = vs;
        *(float4*)&s_in[e * SLD + 128 + l4] = vd;
    }
    // stage attrs + w
    for (int i = t; i < BE * 17; i += 256) {
        int e = i / 17, j = i % 17;
        float v;
        if (j < 8)       v = attr_e[(size_t)s_src[e] * A_ + j];
        else if (j < 16) v = attr_e[(size_t)s_dst[e] * A_ + (j - 8)];
        else             v = w_e[e0 + e];
        s_in[e * SLD + 256 + j] = v;
    }
    __syncthreads();

    const int c0 = (t & 63) * 2;      // 2 consecutive hidden cols
    const int r0 = (t >> 6) * 8;      // 8 edge rows (wave-uniform)

    float acc[8][2];
    float bb0 = b1[c0], bb1 = b1[c0 + 1];
#pragma unroll
    for (int j = 0; j < 8; ++j) { acc[j][0] = bb0; acc[j][1] = bb1; }

    for (int k = 0; k < EIN_; ++k) {
        float wa = w1[k * L_ + c0];
        float wb = w1[k * L_ + c0 + 1];
#pragma unroll
        for (int j = 0; j < 8; ++j) {
            float m = s_in[(r0 + j) * SLD + k];     // wave-broadcast LDS read
            acc[j][0] = fmaf(m, wa, acc[j][0]);
            acc[j][1] = fmaf(m, wb, acc[j][1]);
        }
    }
#pragma unroll
    for (int j = 0; j < 8; ++j) {
        float v0 = acc[j][0], v1 = acc[j][1];
        v0 = v0 / (1.f + __expf(-v0));              // silu
        v1 = v1 / (1.f + __expf(-v1));
        s_h[(r0 + j) * L_ + c0] = v0;
        s_h[(r0 + j) * L_ + c0 + 1] = v1;
    }
    __syncthreads();

    float a2[8][2];
    float cb0 = b2[c0], cb1 = b2[c0 + 1];
#pragma unroll
    for (int j = 0; j < 8; ++j) { a2[j][0] = cb0; a2[j][1] = cb1; }

#pragma unroll 4
    for (int k = 0; k < L_; ++k) {
        float wa = w2[k * L_ + c0];
        float wb = w2[k * L_ + c0 + 1];
#pragma unroll
        for (int j = 0; j < 8; ++j) {
            float m = s_h[(r0 + j) * L_ + k];
            a2[j][0] = fmaf(m, wa, a2[j][0]);
            a2[j][1] = fmaf(m, wb, a2[j][1]);
        }
    }
#pragma unroll
    for (int j = 0; j < 8; ++j) {
        int d = s_dst[r0 + j];
        atomicAdd(&agg[(size_t)d * L_ + c0],     a2[j][0]);
        atomicAdd(&agg[(size_t)d * L_ + c0 + 1], a2[j][1]);
    }
}

// ---------------- node MLP (fused 2-layer MLP + Verlet update) ----------------
// u = [y(128) | agg(128)]; yn = silu(u@nw1+nb1)@nw2+nb2
// tmp=y; y = 2y - y_old - h^2*yn; y_old = tmp
__global__ __launch_bounds__(256) void k_node_mlp(
    float* __restrict__ y, float* __restrict__ y_old, const float* __restrict__ agg,
    const float* __restrict__ nw1, const float* __restrict__ nb1,
    const float* __restrict__ nw2, const float* __restrict__ nb2,
    const float* __restrict__ hvec, int layer) {
    __shared__ float s_u[32 * 256];     // 32768 B
    __shared__ float s_h[32 * L_];      // 16384 B

    const int t  = threadIdx.x;
    const int n0 = blockIdx.x * 32;

    for (int i = t; i < 32 * 32; i += 256) {
        int r = i >> 5, l4 = (i & 31) * 4;
        *(float4*)&s_u[r * 256 + l4]       = *(const float4*)&y[(size_t)(n0 + r) * L_ + l4];
        *(float4*)&s_u[r * 256 + 128 + l4] = *(const float4*)&agg[(size_t)(n0 + r) * L_ + l4];
    }
    __syncthreads();

    const int c0 = (t & 63) * 2;
    const int r0 = (t >> 6) * 8;

    float acc[8][2];
    float bb0 = nb1[c0], bb1 = nb1[c0 + 1];
#pragma unroll
    for (int j = 0; j < 8; ++j) { acc[j][0] = bb0; acc[j][1] = bb1; }

#pragma unroll 4
    for (int k = 0; k < 2 * L_; ++k) {
        float wa = nw1[k * L_ + c0];
        float wb = nw1[k * L_ + c0 + 1];
#pragma unroll
        for (int j = 0; j < 8; ++j) {
            float m = s_u[(r0 + j) * 256 + k];
            acc[j][0] = fmaf(m, wa, acc[j][0]);
            acc[j][1] = fmaf(m, wb, acc[j][1]);
        }
    }
#pragma unroll
    for (int j = 0; j < 8; ++j) {
        float v0 = acc[j][0], v1 = acc[j][1];
        v0 = v0 / (1.f + __expf(-v0));
        v1 = v1 / (1.f + __expf(-v1));
        s_h[(r0 + j) * L_ + c0] = v0;
        s_h[(r0 + j) * L_ + c0 + 1] = v1;
    }
    __syncthreads();

    float a2[8][2];
    float cb0 = nb2[c0], cb1 = nb2[c0 + 1];
#pragma unroll
    for (int j = 0; j < 8; ++j) { a2[j][0] = cb0; a2[j][1] = cb1; }

#pragma unroll 4
    for (int k = 0; k < L_; ++k) {
        float wa = nw2[k * L_ + c0];
        float wb = nw2[k * L_ + c0 + 1];
#pragma unroll
        for (int j = 0; j < 8; ++j) {
            float m = s_h[(r0 + j) * L_ + k];
            a2[j][0] = fmaf(m, wa, a2[j][0]);
            a2[j][1] = fmaf(m, wb, a2[j][1]);
        }
    }

    float hh = hvec[layer];
    float h2 = hh * hh;
#pragma unroll
    for (int j = 0; j < 8; ++j) {
        int n = n0 + r0 + j;
#pragma unroll
        for (int q = 0; q < 2; ++q) {
            int c = c0 + q;
            float yv = s_u[(r0 + j) * 256 + c];     // staged copy of y[n][c]
            float yo = y_old[(size_t)n * L_ + c];
            y_old[(size_t)n * L_ + c] = yv;
            y[(size_t)n * L_ + c] = 2.f * yv - yo - h2 * a2[j][q];
        }
    }
}

// ---------------- host launch ----------------

extern "C" void kernel_launch(void* const* d_in, const int* in_sizes, int n_in,
                              void* d_out, int out_size, void* d_ws, size_t ws_size,
                              hipStream_t stream) {
    const float* x_in      = (const float*)d_in[0];
    // d_in[1] batch: unused
    const int*   node_attr = (const int*)  d_in[2];
    const int*   esrc      = (const int*)  d_in[3];
    const int*   edst      = (const int*)  d_in[4];
    const float* W         = (const float*)d_in[5];
    const float* embed     = (const float*)d_in[6];
    const float* hvec      = (const float*)d_in[7];
    const float* mw1       = (const float*)d_in[8];
    const float* mb1       = (const float*)d_in[9];
    const float* mw2       = (const float*)d_in[10];
    const float* mb2       = (const float*)d_in[11];
    const float* nw1       = (const float*)d_in[12];
    const float* nb1       = (const float*)d_in[13];
    const float* nw2       = (const float*)d_in[14];
    const float* nb2       = (const float*)d_in[15];
    float* out = (float*)d_out;

    float* ws     = (float*)d_ws;
    float* y      = ws;                      // N*L
    float* y_old  = y + (size_t)N_ * L_;     // N*L
    float* agg    = y_old + (size_t)N_ * L_; // N*L
    float* x_cur  = agg + (size_t)N_ * L_;   // N*6
    float* w_e    = x_cur + (size_t)N_ * DIM_IN_; // E
    float* attr_e = w_e + (size_t)E_;        // N*A

    k_init_y<<<(N_ * L_ + 255) / 256, 256, 0, stream>>>(x_in, W, y, y_old);
    k_attr<<<(N_ * A_ + 255) / 256, 256, 0, stream>>>(node_attr, embed, attr_e);

    for (int i = 0; i < NL_; ++i) {
        const float* xp = (i == 0) ? x_in : x_cur;
        if (i > 0)
            k_x<<<(N_ * DIM_IN_ + 255) / 256, 256, 0, stream>>>(y, W, x_cur);
        k_edge_w<<<(E_ + 255) / 256, 256, 0, stream>>>(xp, esrc, edst, w_e);
        hipMemsetAsync(agg, 0, (size_t)N_ * L_ * sizeof(float), stream);
        k_edge_mlp<<<E_ / BE, 256, 0, stream>>>(
            y, attr_e, w_e, esrc, edst,
            mw1 + (size_t)i * EIN_ * L_, mb1 + (size_t)i * L_,
            mw2 + (size_t)i * L_ * L_,   mb2 + (size_t)i * L_, agg);
        k_node_mlp<<<N_ / 32, 256, 0, stream>>>(
            y, y_old, agg,
            nw1 + (size_t)i * 2 * L_ * L_, nb1 + (size_t)i * L_,
            nw2 + (size_t)i * L_ * L_,     nb2 + (size_t)i * L_,
            hvec, i);
    }

    k_x<<<(N_ * DIM_IN_ + 255) / 256, 256, 0, stream>>>(y, W, out);
    k_scalars<<<1, 4, 0, stream>>>(out + (size_t)N_ * DIM_IN_);
}

// Round 3
// 717.565 us; speedup vs baseline: 2.2814x; 2.2814x over previous
//
#include <hip/hip_runtime.h>
#include <hip/hip_bf16.h>
#include <math.h>

// Problem constants (from reference)
#define N_ 20000
#define E_ 160000
#define DIM_IN_ 6
#define L_ 128
#define A_ 8
#define NL_ 4
#define EIN_ 273          // 2*L + 2*A + 1
#define MAX_R_ 50.0f

typedef unsigned short u16;
typedef short bf16x8 __attribute__((ext_vector_type(8)));    // 8 bf16 in 4 VGPRs
typedef u16   u16x8  __attribute__((ext_vector_type(8)));
typedef float f32x4  __attribute__((ext_vector_type(4)));

static __device__ __forceinline__ float bf2f(u16 u) {
    return __uint_as_float(((unsigned)u) << 16);
}
static __device__ __forceinline__ u16 f2bf(float f) {       // RNE, no NaN inputs here
    unsigned b = __float_as_uint(f);
    return (u16)((b + 0x7FFF + ((b >> 16) & 1)) >> 16);
}
static __device__ __forceinline__ float silu(float v) {
    return v / (1.f + __expf(-v));
}

// ---------------- setup kernels ----------------

__global__ void k_init_y(const float* __restrict__ x, const float* __restrict__ W,
                         float* __restrict__ y, float* __restrict__ y_old) {
    int tid = blockIdx.x * blockDim.x + threadIdx.x;   // N_*L_ threads
    if (tid >= N_ * L_) return;
    int n = tid >> 7, l = tid & 127;
    float a = 0.f;
#pragma unroll
    for (int d = 0; d < DIM_IN_; ++d) a = fmaf(x[n * DIM_IN_ + d], W[l * DIM_IN_ + d], a);
    y[tid] = a;
    y_old[tid] = a;
}

__global__ void k_attr(const int* __restrict__ node_attr, const float* __restrict__ embed,
                       float* __restrict__ attr_e) {
    int tid = blockIdx.x * blockDim.x + threadIdx.x;   // N_*A_ threads
    if (tid >= N_ * A_) return;
    int n = tid >> 3, a = tid & 7;
    attr_e[tid] = embed[node_attr[n] * A_ + a];
}

// x_out[n][d] = sum_l y[n][l] * W[l][d]
__global__ void k_x(const float* __restrict__ y, const float* __restrict__ W,
                    float* __restrict__ x_out) {
    int tid = blockIdx.x * blockDim.x + threadIdx.x;   // N_*6 threads
    if (tid >= N_ * DIM_IN_) return;
    int n = tid / DIM_IN_, d = tid % DIM_IN_;
    float a = 0.f;
    for (int l = 0; l < L_; ++l) a = fmaf(y[(size_t)n * L_ + l], W[l * DIM_IN_ + d], a);
    x_out[tid] = a;
}

__global__ void k_edge_w(const float* __restrict__ xp, const int* __restrict__ esrc,
                         const int* __restrict__ edst, float* __restrict__ w_e) {
    int e = blockIdx.x * blockDim.x + threadIdx.x;
    if (e >= E_) return;
    int s = esrc[e], d = edst[e];
    float dx = xp[s * DIM_IN_ + 0] - xp[d * DIM_IN_ + 0];
    float dy = xp[s * DIM_IN_ + 1] - xp[d * DIM_IN_ + 1];
    float dz = xp[s * DIM_IN_ + 2] - xp[d * DIM_IN_ + 2];
    float len = sqrtf(dx * dx + dy * dy + dz * dz);
    float u = 2.f * (len / MAX_R_ - 1.f);
    float cv;
    if (u > 0.f)       cv = 0.f;
    else if (u < -1.f) cv = 1.f;
    else               cv = 0.5f * (1.f - cosf(3.14159265358979323846f * u));
    w_e[e] = cv / len;
}

__global__ void k_scalars(float* __restrict__ tail) {
    int j = threadIdx.x;
    if (j < 4) tail[j] = (j < 2) ? -1.0f : 0.0f;
}

// ---------------- weight prep (once per launch) ----------------
// w1cat_t[i][cc][k] (bf16): cc<128 -> w1[i][k][cc]         (src half)
//                           cc>=128 -> w1[i][128+k][cc-128] (dst half)
// w2t[i][c][k]     (bf16): w2[i][k][c]
// w1attr[i][j][cc] (f32):  cc<128 -> w1[i][256+j][cc] else w1[i][264+j][cc-128]
// bcat[i][cc]      (f32):  cc<128 -> 0 else b1[i][cc-128]
// wr272[i][c]      (f32):  w1[i][272][c]
__global__ void k_prep(const float* __restrict__ mw1, const float* __restrict__ mb1,
                       const float* __restrict__ mw2,
                       u16* __restrict__ w1cat_t, u16* __restrict__ w2t,
                       float* __restrict__ w1attr, float* __restrict__ bcat,
                       float* __restrict__ wr272) {
    int idx = blockIdx.x * 256 + threadIdx.x;
    if (idx < NL_ * 256 * 128) {
        int i = idx >> 15; int rem = idx & 32767; int cc = rem >> 7; int k = rem & 127;
        int row = (cc < 128) ? k : 128 + k;
        w1cat_t[idx] = f2bf(mw1[(size_t)i * EIN_ * L_ + row * L_ + (cc & 127)]);
        return;
    }
    idx -= NL_ * 256 * 128;
    if (idx < NL_ * 128 * 128) {
        int i = idx >> 14; int rem = idx & 16383; int c = rem >> 7; int k = rem & 127;
        w2t[idx] = f2bf(mw2[(size_t)i * L_ * L_ + k * L_ + c]);
        return;
    }
    idx -= NL_ * 128 * 128;
    if (idx < NL_ * 8 * 256) {
        int i = idx >> 11; int rem = idx & 2047; int j = rem >> 8; int cc = rem & 255;
        int row = (cc < 128) ? 256 + j : 264 + j;
        w1attr[idx] = mw1[(size_t)i * EIN_ * L_ + row * L_ + (cc & 127)];
        return;
    }
    idx -= NL_ * 8 * 256;
    if (idx < NL_ * 256) {
        int i = idx >> 8; int cc = idx & 255;
        bcat[idx] = (cc < 128) ? 0.f : mb1[i * L_ + cc - 128];
        return;
    }
    idx -= NL_ * 256;
    if (idx < NL_ * 128) {
        int i = idx >> 7; int c = idx & 127;
        wr272[idx] = mw1[(size_t)i * EIN_ * L_ + 272 * L_ + c];
    }
}
#define PREP_TOTAL (NL_*256*128 + NL_*128*128 + NL_*8*256 + NL_*256 + NL_*128)

// ---------------- per-node projection GEMM (bf16 MFMA) ----------------
// P[n][cc] = sum_k y[n][k]*w1cat[k][cc] + sum_j attr[n][j]*w1attr[j][cc] + bcat[cc]
// 64 rows per block, 128 cols per block (blockIdx.y selects col half).
__global__ __launch_bounds__(256) void k_pre(
    const float* __restrict__ y, const float* __restrict__ attr_e,
    const u16* __restrict__ w1cat_t,   // layer slice [256][128] (row=cc, col=k)
    const float* __restrict__ w1attr,  // layer slice [8][256]
    const float* __restrict__ bcat,    // layer slice [256]
    u16* __restrict__ P) {             // [N][256]
    __shared__ u16   s_a[64 * 136];    // y rows, bf16, padded stride
    __shared__ float s_attr[64 * 8];
    __shared__ float s_w1a[8 * 128];
    __shared__ float s_bc[128];

    const int t  = threadIdx.x;
    const int n0 = blockIdx.x * 64;
    const int cb = blockIdx.y;         // col half: 0 -> src part, 1 -> dst part

    // stage A: y rows -> bf16 LDS (zeros for OOB rows)
    for (int i = t; i < 64 * 16; i += 256) {
        int r = i >> 4, ch = i & 15;
        int n = n0 + r;
        u16x8 v;
        if (n < N_) {
            const float4* p = (const float4*)&y[(size_t)n * L_ + ch * 8];
            float4 f0 = p[0], f1 = p[1];
            v[0] = f2bf(f0.x); v[1] = f2bf(f0.y); v[2] = f2bf(f0.z); v[3] = f2bf(f0.w);
            v[4] = f2bf(f1.x); v[5] = f2bf(f1.y); v[6] = f2bf(f1.z); v[7] = f2bf(f1.w);
        } else {
#pragma unroll
            for (int j = 0; j < 8; ++j) v[j] = 0;
        }
        *(u16x8*)&s_a[r * 136 + ch * 8] = v;
    }
    // stage attr rows
    for (int i = t; i < 64 * 2; i += 256) {
        int r = i >> 1, half = i & 1;
        int n = n0 + r;
        float4 v = make_float4(0.f, 0.f, 0.f, 0.f);
        if (n < N_) v = *(const float4*)&attr_e[(size_t)n * A_ + half * 4];
        *(float4*)&s_attr[r * 8 + half * 4] = v;
    }
    // stage attr-weight slice + bias
    for (int i = t; i < 8 * 128; i += 256) {
        int j = i >> 7, c = i & 127;
        s_w1a[i] = w1attr[j * 256 + cb * 128 + c];
    }
    if (t < 128) s_bc[t] = bcat[cb * 128 + t];
    __syncthreads();

    const int l  = t & 63, w = t >> 6;
    const int r0 = w * 16;
    const int lr = l & 15, lk = l >> 4;

    bf16x8 a[4];
#pragma unroll
    for (int ks = 0; ks < 4; ++ks)
        a[ks] = *(const bf16x8*)&s_a[(r0 + lr) * 136 + ks * 32 + lk * 8];

#pragma unroll
    for (int ct = 0; ct < 8; ++ct) {
        int c = ct * 16 + lr;
        float bb = s_bc[c];
        f32x4 acc = {bb, bb, bb, bb};
#pragma unroll
        for (int ks = 0; ks < 4; ++ks) {
            bf16x8 b = *(const bf16x8*)&w1cat_t[(size_t)(cb * 128 + c) * 128 + ks * 32 + lk * 8];
            acc = __builtin_amdgcn_mfma_f32_16x16x32_bf16(a[ks], b, acc, 0, 0, 0);
        }
#pragma unroll
        for (int i = 0; i < 4; ++i) {
            int r = r0 + lk * 4 + i;
            int n = n0 + r;
            if (n < N_) {
                float v = acc[i];
#pragma unroll
                for (int j = 0; j < 8; ++j) v = fmaf(s_attr[r * 8 + j], s_w1a[j * 128 + c], v);
                P[(size_t)n * 256 + cb * 128 + c] = f2bf(v);
            }
        }
    }
}

// ---------------- edge kernel: gather + silu + bf16 MFMA GEMM2 + scatter ----------------
// h[e] = silu(P[src][0:128] + P[dst][128:256] + w_e*wr272)
// m[e] = h[e] @ w2 + b2 ; agg[dst] += m[e]
__global__ __launch_bounds__(256) void k_edge_mfma(
    const u16* __restrict__ P, const float* __restrict__ w_e,
    const int* __restrict__ esrc, const int* __restrict__ edst,
    const u16* __restrict__ w2t,    // layer slice [128][128] (row=c, col=k)
    const float* __restrict__ wr272,// layer slice [128]
    const float* __restrict__ b2,   // layer slice [128]
    float* __restrict__ agg) {
    __shared__ u16   s_h[64 * 136];
    __shared__ int   s_src[64], s_dst[64];
    __shared__ float s_wr[128], s_b2[128];

    const int t  = threadIdx.x;
    const int e0 = blockIdx.x * 64;

    if (t < 64) { s_src[t] = esrc[e0 + t]; s_dst[t] = edst[e0 + t]; }
    else if (t >= 128) { int c = t - 128; s_wr[c] = wr272[c]; s_b2[c] = b2[c]; }
    __syncthreads();

    // compute hidden rows (4 threads per edge, 32 cols each)
    {
        int e = t >> 2, q = t & 3;
        int src = s_src[e], dst = s_dst[e];
        float we = w_e[e0 + e];
        const u16* ps = &P[(size_t)src * 256];
        const u16* pd = &P[(size_t)dst * 256 + 128];
#pragma unroll
        for (int j = 0; j < 4; ++j) {
            int c = j * 32 + q * 8;
            u16x8 av = *(const u16x8*)&ps[c];
            u16x8 bv = *(const u16x8*)&pd[c];
            u16x8 o;
#pragma unroll
            for (int jj = 0; jj < 8; ++jj) {
                float v = bf2f(av[jj]) + bf2f(bv[jj]) + we * s_wr[c + jj];
                o[jj] = f2bf(silu(v));
            }
            *(u16x8*)&s_h[e * 136 + c] = o;
        }
    }
    __syncthreads();

    const int l  = t & 63, w = t >> 6;
    const int r0 = w * 16;               // 16 edge rows per wave
    const int lr = l & 15, lk = l >> 4;

    bf16x8 a[4];
#pragma unroll
    for (int ks = 0; ks < 4; ++ks)
        a[ks] = *(const bf16x8*)&s_h[(r0 + lr) * 136 + ks * 32 + lk * 8];

#pragma unroll
    for (int ct = 0; ct < 8; ++ct) {
        int c = ct * 16 + lr;
        float bb = s_b2[c];
        f32x4 acc = {bb, bb, bb, bb};
#pragma unroll
        for (int ks = 0; ks < 4; ++ks) {
            bf16x8 b = *(const bf16x8*)&w2t[(size_t)c * 128 + ks * 32 + lk * 8];
            acc = __builtin_amdgcn_mfma_f32_16x16x32_bf16(a[ks], b, acc, 0, 0, 0);
        }
#pragma unroll
        for (int i = 0; i < 4; ++i) {
            int r = r0 + lk * 4 + i;
            atomicAdd(&agg[(size_t)s_dst[r] * L_ + c], acc[i]);
        }
    }
}

// ---------------- node MLP (fp32, fused 2-layer MLP + Verlet update) ----------------
__global__ __launch_bounds__(256) void k_node_mlp(
    float* __restrict__ y, float* __restrict__ y_old, const float* __restrict__ agg,
    const float* __restrict__ nw1, const float* __restrict__ nb1,
    const float* __restrict__ nw2, const float* __restrict__ nb2,
    const float* __restrict__ hvec, int layer) {
    __shared__ float s_u[32 * 256];
    __shared__ float s_h[32 * L_];

    const int t  = threadIdx.x;
    const int n0 = blockIdx.x * 32;

    for (int i = t; i < 32 * 32; i += 256) {
        int r = i >> 5, l4 = (i & 31) * 4;
        *(float4*)&s_u[r * 256 + l4]       = *(const float4*)&y[(size_t)(n0 + r) * L_ + l4];
        *(float4*)&s_u[r * 256 + 128 + l4] = *(const float4*)&agg[(size_t)(n0 + r) * L_ + l4];
    }
    __syncthreads();

    const int c0 = (t & 63) * 2;
    const int r0 = (t >> 6) * 8;

    float acc[8][2];
    float bb0 = nb1[c0], bb1 = nb1[c0 + 1];
#pragma unroll
    for (int j = 0; j < 8; ++j) { acc[j][0] = bb0; acc[j][1] = bb1; }

#pragma unroll 4
    for (int k = 0; k < 2 * L_; ++k) {
        float wa = nw1[k * L_ + c0];
        float wb = nw1[k * L_ + c0 + 1];
#pragma unroll
        for (int j = 0; j < 8; ++j) {
            float m = s_u[(r0 + j) * 256 + k];
            acc[j][0] = fmaf(m, wa, acc[j][0]);
            acc[j][1] = fmaf(m, wb, acc[j][1]);
        }
    }
#pragma unroll
    for (int j = 0; j < 8; ++j) {
        s_h[(r0 + j) * L_ + c0]     = silu(acc[j][0]);
        s_h[(r0 + j) * L_ + c0 + 1] = silu(acc[j][1]);
    }
    __syncthreads();

    float a2[8][2];
    float cb0 = nb2[c0], cb1 = nb2[c0 + 1];
#pragma unroll
    for (int j = 0; j < 8; ++j) { a2[j][0] = cb0; a2[j][1] = cb1; }

#pragma unroll 4
    for (int k = 0; k < L_; ++k) {
        float wa = nw2[k * L_ + c0];
        float wb = nw2[k * L_ + c0 + 1];
#pragma unroll
        for (int j = 0; j < 8; ++j) {
            float m = s_h[(r0 + j) * L_ + k];
            a2[j][0] = fmaf(m, wa, a2[j][0]);
            a2[j][1] = fmaf(m, wb, a2[j][1]);
        }
    }

    float hh = hvec[layer];
    float h2 = hh * hh;
#pragma unroll
    for (int j = 0; j < 8; ++j) {
        int n = n0 + r0 + j;
#pragma unroll
        for (int q = 0; q < 2; ++q) {
            int c = c0 + q;
            float yv = s_u[(r0 + j) * 256 + c];
            float yo = y_old[(size_t)n * L_ + c];
            y_old[(size_t)n * L_ + c] = yv;
            y[(size_t)n * L_ + c] = 2.f * yv - yo - h2 * a2[j][q];
        }
    }
}

// ---------------- host launch ----------------

extern "C" void kernel_launch(void* const* d_in, const int* in_sizes, int n_in,
                              void* d_out, int out_size, void* d_ws, size_t ws_size,
                              hipStream_t stream) {
    const float* x_in      = (const float*)d_in[0];
    const int*   node_attr = (const int*)  d_in[2];
    const int*   esrc      = (const int*)  d_in[3];
    const int*   edst      = (const int*)  d_in[4];
    const float* W         = (const float*)d_in[5];
    const float* embed     = (const float*)d_in[6];
    const float* hvec      = (const float*)d_in[7];
    const float* mw1       = (const float*)d_in[8];
    const float* mb1       = (const float*)d_in[9];
    const float* mw2       = (const float*)d_in[10];
    const float* mb2g      = (const float*)d_in[11];
    const float* nw1       = (const float*)d_in[12];
    const float* nb1       = (const float*)d_in[13];
    const float* nw2       = (const float*)d_in[14];
    const float* nb2       = (const float*)d_in[15];
    float* out = (float*)d_out;

    char* base = (char*)d_ws;
    float* y       = (float*)base; base += (size_t)N_ * L_ * 4;        // 10.24 MB
    float* y_old   = (float*)base; base += (size_t)N_ * L_ * 4;
    float* agg     = (float*)base; base += (size_t)N_ * L_ * 4;
    float* x_cur   = (float*)base; base += (size_t)N_ * DIM_IN_ * 4;
    float* w_e     = (float*)base; base += (size_t)E_ * 4;
    float* attr_e  = (float*)base; base += (size_t)N_ * A_ * 4;
    u16*   P       = (u16*)  base; base += (size_t)N_ * 256 * 2;       // 10.24 MB
    u16*   w1cat_t = (u16*)  base; base += (size_t)NL_ * 256 * 128 * 2;
    u16*   w2t     = (u16*)  base; base += (size_t)NL_ * 128 * 128 * 2;
    float* w1attr  = (float*)base; base += (size_t)NL_ * 8 * 256 * 4;
    float* bcat    = (float*)base; base += (size_t)NL_ * 256 * 4;
    float* wr272   = (float*)base; base += (size_t)NL_ * 128 * 4;

    k_prep<<<(PREP_TOTAL + 255) / 256, 256, 0, stream>>>(
        mw1, mb1, mw2, w1cat_t, w2t, w1attr, bcat, wr272);
    k_init_y<<<(N_ * L_ + 255) / 256, 256, 0, stream>>>(x_in, W, y, y_old);
    k_attr<<<(N_ * A_ + 255) / 256, 256, 0, stream>>>(node_attr, embed, attr_e);

    for (int i = 0; i < NL_; ++i) {
        const float* xp = (i == 0) ? x_in : x_cur;
        if (i > 0)
            k_x<<<(N_ * DIM_IN_ + 255) / 256, 256, 0, stream>>>(y, W, x_cur);
        k_edge_w<<<(E_ + 255) / 256, 256, 0, stream>>>(xp, esrc, edst, w_e);
        k_pre<<<dim3(313, 2), 256, 0, stream>>>(
            y, attr_e,
            w1cat_t + (size_t)i * 256 * 128,
            w1attr + (size_t)i * 8 * 256,
            bcat + (size_t)i * 256,
            P);
        hipMemsetAsync(agg, 0, (size_t)N_ * L_ * sizeof(float), stream);
        k_edge_mfma<<<E_ / 64, 256, 0, stream>>>(
            P, w_e, esrc, edst,
            w2t + (size_t)i * 128 * 128,
            wr272 + (size_t)i * 128,
            mb2g + (size_t)i * 128,
            agg);
        k_node_mlp<<<N_ / 32, 256, 0, stream>>>(
            y, y_old, agg,
            nw1 + (size_t)i * 2 * L_ * L_, nb1 + (size_t)i * L_,
            nw2 + (size_t)i * L_ * L_,     nb2 + (size_t)i * L_,
            hvec, i);
    }

    k_x<<<(N_ * DIM_IN_ + 255) / 256, 256, 0, stream>>>(y, W, out);
    k_scalars<<<1, 4, 0, stream>>>(out + (size_t)N_ * DIM_IN_);
}

// Round 4
// 522.542 us; speedup vs baseline: 3.1329x; 1.3732x over previous
//
#include <hip/hip_runtime.h>
#include <hip/hip_bf16.h>
#include <math.h>

// Problem constants (from reference)
#define N_ 20000
#define NPAD_ 20032       // 313*64, padded row count for fragment loads
#define E_ 160000
#define DIM_IN_ 6
#define L_ 128
#define A_ 8
#define NL_ 4
#define EIN_ 273          // 2*L + 2*A + 1
#define MAX_R_ 50.0f

typedef unsigned short u16;
typedef short bf16x8 __attribute__((ext_vector_type(8)));    // 8 bf16 in 4 VGPRs
typedef u16   u16x8  __attribute__((ext_vector_type(8)));
typedef float f32x4  __attribute__((ext_vector_type(4)));

static __device__ __forceinline__ float bf2f(u16 u) {
    return __uint_as_float(((unsigned)u) << 16);
}
static __device__ __forceinline__ u16 f2bf(float f) {       // RNE
    unsigned b = __float_as_uint(f);
    return (u16)((b + 0x7FFF + ((b >> 16) & 1)) >> 16);
}
static __device__ __forceinline__ float silu(float v) {
    return v / (1.f + __expf(-v));
}

// ---------------- setup kernels ----------------

__global__ void k_init_y(const float* __restrict__ x, const float* __restrict__ W,
                         float* __restrict__ y, float* __restrict__ y_old) {
    int tid = blockIdx.x * blockDim.x + threadIdx.x;
    if (tid >= N_ * L_) return;
    int n = tid >> 7, l = tid & 127;
    float a = 0.f;
#pragma unroll
    for (int d = 0; d < DIM_IN_; ++d) a = fmaf(x[n * DIM_IN_ + d], W[l * DIM_IN_ + d], a);
    y[tid] = a;
    y_old[tid] = a;
}

__global__ void k_attr(const int* __restrict__ node_attr, const float* __restrict__ embed,
                       float* __restrict__ attr_e) {
    int tid = blockIdx.x * blockDim.x + threadIdx.x;
    if (tid >= N_ * A_) return;
    int n = tid >> 3, a = tid & 7;
    attr_e[tid] = embed[node_attr[n] * A_ + a];
}

// x_out[n][d] = sum_l y[n][l] * W[l][d]
__global__ void k_x(const float* __restrict__ y, const float* __restrict__ W,
                    float* __restrict__ x_out) {
    int tid = blockIdx.x * blockDim.x + threadIdx.x;
    if (tid >= N_ * DIM_IN_) return;
    int n = tid / DIM_IN_, d = tid % DIM_IN_;
    float a = 0.f;
    for (int l = 0; l < L_; ++l) a = fmaf(y[(size_t)n * L_ + l], W[l * DIM_IN_ + d], a);
    x_out[tid] = a;
}

// edge cutoff weight, written directly in CSR order via perm
__global__ void k_edge_w(const float* __restrict__ xp, const int* __restrict__ esrc,
                         const int* __restrict__ edst, const int* __restrict__ perm,
                         float* __restrict__ w_csr) {
    int e = blockIdx.x * blockDim.x + threadIdx.x;
    if (e >= E_) return;
    int s = esrc[e], d = edst[e];
    float dx = xp[s * DIM_IN_ + 0] - xp[d * DIM_IN_ + 0];
    float dy = xp[s * DIM_IN_ + 1] - xp[d * DIM_IN_ + 1];
    float dz = xp[s * DIM_IN_ + 2] - xp[d * DIM_IN_ + 2];
    float len = sqrtf(dx * dx + dy * dy + dz * dz);
    float u = 2.f * (len / MAX_R_ - 1.f);
    float cv;
    if (u > 0.f)       cv = 0.f;
    else if (u < -1.f) cv = 1.f;
    else               cv = 0.5f * (1.f - cosf(3.14159265358979323846f * u));
    w_csr[perm[e]] = cv / len;
}

__global__ void k_scalars(float* __restrict__ tail) {
    int j = threadIdx.x;
    if (j < 4) tail[j] = (j < 2) ? -1.0f : 0.0f;
}

// ---------------- CSR build (edge list is static across layers) ----------------

__global__ void k_hist(const int* __restrict__ edst, int* __restrict__ deg) {
    int e = blockIdx.x * blockDim.x + threadIdx.x;
    if (e < E_) atomicAdd(&deg[edst[e]], 1);
}

#define SCAN_CH 20   // 1024*20 = 20480 >= N_
__global__ __launch_bounds__(1024) void k_scan(const int* __restrict__ deg,
                                               int* __restrict__ rowptr,
                                               int* __restrict__ cursor) {
    __shared__ int s[1024];
    int t = threadIdx.x;
    int base = t * SCAN_CH;
    int local[SCAN_CH];
    int sum = 0;
#pragma unroll
    for (int j = 0; j < SCAN_CH; ++j) {
        int n = base + j;
        int d = (n < N_) ? deg[n] : 0;
        local[j] = d; sum += d;
    }
    s[t] = sum;
    __syncthreads();
    for (int off = 1; off < 1024; off <<= 1) {
        int v = (t >= off) ? s[t - off] : 0;
        __syncthreads();
        s[t] += v;
        __syncthreads();
    }
    int run = t ? s[t - 1] : 0;
#pragma unroll
    for (int j = 0; j < SCAN_CH; ++j) {
        int n = base + j;
        if (n < N_) { rowptr[n] = run; cursor[n] = run; run += local[j]; }
    }
    if (t == 1023) rowptr[N_] = run;   // == E_
}

__global__ void k_fill(const int* __restrict__ esrc, const int* __restrict__ edst,
                       int* __restrict__ cursor, int* __restrict__ perm,
                       int* __restrict__ csr_src) {
    int e = blockIdx.x * blockDim.x + threadIdx.x;
    if (e >= E_) return;
    int p = atomicAdd(&cursor[edst[e]], 1);
    perm[e] = p;
    csr_src[p] = esrc[e];
}

// ---------------- weight prep (once per launch) ----------------
// w1cat_t[i][cc][k] (bf16): cc<128 -> w1[k][cc] ; cc>=128 -> w1[128+k][cc-128]
// nw1at[i][c][k]   (bf16): nw1[k][c]          (first-half rows of nw1)
// nw2t[i][c][k]    (bf16): nw2[k][c]
// w1attr[i][j][cc] (f32):  cc<128 -> w1[256+j][cc] else w1[264+j][cc-128]
// bcat[i][cc]      (f32):  cc<128 -> 0 else b1[cc-128]
// wr272[i][c]      (f32):  w1[272][c]
__global__ void k_prep(const float* __restrict__ mw1, const float* __restrict__ mb1,
                       const float* __restrict__ nw1, const float* __restrict__ nw2,
                       u16* __restrict__ w1cat_t, u16* __restrict__ nw1at,
                       u16* __restrict__ nw2t,
                       float* __restrict__ w1attr, float* __restrict__ bcat,
                       float* __restrict__ wr272) {
    int idx = blockIdx.x * 256 + threadIdx.x;
    if (idx < NL_ * 256 * 128) {
        int i = idx >> 15; int rem = idx & 32767; int cc = rem >> 7; int k = rem & 127;
        int row = (cc < 128) ? k : 128 + k;
        w1cat_t[idx] = f2bf(mw1[(size_t)i * EIN_ * L_ + row * L_ + (cc & 127)]);
        return;
    }
    idx -= NL_ * 256 * 128;
    if (idx < NL_ * 128 * 128) {
        int i = idx >> 14; int rem = idx & 16383; int c = rem >> 7; int k = rem & 127;
        nw1at[idx] = f2bf(nw1[(size_t)i * 2 * L_ * L_ + k * L_ + c]);
        return;
    }
    idx -= NL_ * 128 * 128;
    if (idx < NL_ * 128 * 128) {
        int i = idx >> 14; int rem = idx & 16383; int c = rem >> 7; int k = rem & 127;
        nw2t[idx] = f2bf(nw2[(size_t)i * L_ * L_ + k * L_ + c]);
        return;
    }
    idx -= NL_ * 128 * 128;
    if (idx < NL_ * 8 * 256) {
        int i = idx >> 11; int rem = idx & 2047; int j = rem >> 8; int cc = rem & 255;
        int row = (cc < 128) ? 256 + j : 264 + j;
        w1attr[idx] = mw1[(size_t)i * EIN_ * L_ + row * L_ + (cc & 127)];
        return;
    }
    idx -= NL_ * 8 * 256;
    if (idx < NL_ * 256) {
        int i = idx >> 8; int cc = idx & 255;
        bcat[idx] = (cc < 128) ? 0.f : mb1[i * L_ + cc - 128];
        return;
    }
    idx -= NL_ * 256;
    if (idx < NL_ * 128) {
        int i = idx >> 7; int c = idx & 127;
        wr272[idx] = mw1[(size_t)i * EIN_ * L_ + 272 * L_ + c];
    }
}
#define PREP_TOTAL (NL_*256*128 + 2*NL_*128*128 + NL_*8*256 + NL_*256 + NL_*128)

// W2nt[i][c][k] = sum_j w2[i][k][j] * nw1[i][128+j][c]   (bf16, transposed for B-frag)
// bvec[i][c]   = sum_j b2[i][j]    * nw1[i][128+j][c]   (f32)
__global__ void k_prep2(const float* __restrict__ mw2, const float* __restrict__ mb2,
                        const float* __restrict__ nw1,
                        u16* __restrict__ W2nt, float* __restrict__ bvec) {
    int idx = blockIdx.x * 256 + threadIdx.x;
    if (idx < NL_ * 128 * 128) {
        int i = idx >> 14; int rem = idx & 16383; int c = rem >> 7; int k = rem & 127;
        const float* w2row = &mw2[(size_t)i * L_ * L_ + k * L_];
        const float* nb    = &nw1[(size_t)i * 2 * L_ * L_ + 128 * L_ + c];
        float a = 0.f;
        for (int j = 0; j < 128; ++j) a = fmaf(w2row[j], nb[(size_t)j * L_], a);
        W2nt[idx] = f2bf(a);
        return;
    }
    idx -= NL_ * 128 * 128;
    if (idx < NL_ * 128) {
        int i = idx >> 7; int c = idx & 127;
        const float* b2 = &mb2[i * L_];
        const float* nb = &nw1[(size_t)i * 2 * L_ * L_ + 128 * L_ + c];
        float a = 0.f;
        for (int j = 0; j < 128; ++j) a = fmaf(b2[j], nb[(size_t)j * L_], a);
        bvec[idx] = a;
    }
}
#define PREP2_TOTAL (NL_*128*128 + NL_*128)

// ---------------- per-node projection GEMM (bf16 MFMA) ----------------
// P[n][cc] = sum_k y[n][k]*w1cat[k][cc] + sum_j attr[n][j]*w1attr[j][cc] + bcat[cc]
__global__ __launch_bounds__(256) void k_pre(
    const float* __restrict__ y, const float* __restrict__ attr_e,
    const u16* __restrict__ w1cat_t,   // layer slice [256][128]
    const float* __restrict__ w1attr,  // layer slice [8][256]
    const float* __restrict__ bcat,    // layer slice [256]
    u16* __restrict__ P) {             // [N][256]
    __shared__ u16   s_a[64 * 136];
    __shared__ float s_attr[64 * 8];
    __shared__ float s_w1a[8 * 128];
    __shared__ float s_bc[128];

    const int t  = threadIdx.x;
    const int n0 = blockIdx.x * 64;
    const int cb = blockIdx.y;

    for (int i = t; i < 64 * 16; i += 256) {
        int r = i >> 4, ch = i & 15;
        int n = n0 + r;
        u16x8 v;
        if (n < N_) {
            const float4* p = (const float4*)&y[(size_t)n * L_ + ch * 8];
            float4 f0 = p[0], f1 = p[1];
            v[0] = f2bf(f0.x); v[1] = f2bf(f0.y); v[2] = f2bf(f0.z); v[3] = f2bf(f0.w);
            v[4] = f2bf(f1.x); v[5] = f2bf(f1.y); v[6] = f2bf(f1.z); v[7] = f2bf(f1.w);
        } else {
#pragma unroll
            for (int j = 0; j < 8; ++j) v[j] = 0;
        }
        *(u16x8*)&s_a[r * 136 + ch * 8] = v;
    }
    for (int i = t; i < 64 * 2; i += 256) {
        int r = i >> 1, half = i & 1;
        int n = n0 + r;
        float4 v = make_float4(0.f, 0.f, 0.f, 0.f);
        if (n < N_) v = *(const float4*)&attr_e[(size_t)n * A_ + half * 4];
        *(float4*)&s_attr[r * 8 + half * 4] = v;
    }
    for (int i = t; i < 8 * 128; i += 256) {
        int j = i >> 7, c = i & 127;
        s_w1a[i] = w1attr[j * 256 + cb * 128 + c];
    }
    if (t < 128) s_bc[t] = bcat[cb * 128 + t];
    __syncthreads();

    const int l  = t & 63, w = t >> 6;
    const int r0 = w * 16;
    const int lr = l & 15, lk = l >> 4;

    bf16x8 a[4];
#pragma unroll
    for (int ks = 0; ks < 4; ++ks)
        a[ks] = *(const bf16x8*)&s_a[(r0 + lr) * 136 + ks * 32 + lk * 8];

#pragma unroll
    for (int ct = 0; ct < 8; ++ct) {
        int c = ct * 16 + lr;
        float bb = s_bc[c];
        f32x4 acc = {bb, bb, bb, bb};
#pragma unroll
        for (int ks = 0; ks < 4; ++ks) {
            bf16x8 b = *(const bf16x8*)&w1cat_t[(size_t)(cb * 128 + c) * 128 + ks * 32 + lk * 8];
            acc = __builtin_amdgcn_mfma_f32_16x16x32_bf16(a[ks], b, acc, 0, 0, 0);
        }
#pragma unroll
        for (int i = 0; i < 4; ++i) {
            int r = r0 + lk * 4 + i;
            int n = n0 + r;
            if (n < N_) {
                float v = acc[i];
#pragma unroll
                for (int j = 0; j < 8; ++j) v = fmaf(s_attr[r * 8 + j], s_w1a[j * 128 + c], v);
                P[(size_t)n * 256 + cb * 128 + c] = f2bf(v);
            }
        }
    }
}

// ---------------- CSR aggregation: Hsum[n] = sum_{e->n} silu(P[src]+P[n][128:]+w*wr272) ----
// 64 lanes per node, 2 cols per lane; accumulate in fp32 registers; no atomics.
__global__ __launch_bounds__(256) void k_agg(
    const u16* __restrict__ P, const float* __restrict__ w_csr,
    const int* __restrict__ csr_src, const int* __restrict__ rowptr,
    const float* __restrict__ wr272,   // layer slice [128]
    u16* __restrict__ Hsum) {          // [NPAD][128]
    const int t = threadIdx.x;
    const int node = blockIdx.x * 4 + (t >> 6);   // grid = 5000 blocks exactly
    const int l = t & 63;

    const int beg = rowptr[node], end = rowptr[node + 1];
    const float wr0 = wr272[2 * l], wr1 = wr272[2 * l + 1];
    unsigned pdu = *(const unsigned*)&P[(size_t)node * 256 + 128 + 2 * l];
    const float pd0 = bf2f((u16)pdu), pd1 = bf2f((u16)(pdu >> 16));

    float h0 = 0.f, h1 = 0.f;
    for (int i = beg; i < end; ++i) {
        int s = csr_src[i];
        float w = w_csr[i];
        unsigned psu = *(const unsigned*)&P[(size_t)s * 256 + 2 * l];
        float v0 = bf2f((u16)psu)         + pd0 + w * wr0;
        float v1 = bf2f((u16)(psu >> 16)) + pd1 + w * wr1;
        h0 += silu(v0);
        h1 += silu(v1);
    }
    unsigned out = (unsigned)f2bf(h0) | ((unsigned)f2bf(h1) << 16);
    *(unsigned*)&Hsum[(size_t)node * 128 + 2 * l] = out;
}

// ---------------- node MLP (bf16 MFMA) + Verlet update ----------------
// acc1 = y@nw1a + Hsum@W2n + deg*bvec + nb1 ; hid = silu(acc1)
// yn = hid@nw2 + nb2 ; tmp=y; y = 2y - y_old - h^2*yn; y_old = tmp
__global__ __launch_bounds__(256) void k_node(
    float* __restrict__ y, float* __restrict__ y_old,
    const u16* __restrict__ Hsum, const int* __restrict__ rowptr,
    const u16* __restrict__ nw1at,  // layer slice [128][128]
    const u16* __restrict__ W2nt,   // layer slice [128][128]
    const u16* __restrict__ nw2t,   // layer slice [128][128]
    const float* __restrict__ bvec, // layer slice [128]
    const float* __restrict__ nb1,  // layer slice [128]
    const float* __restrict__ nb2,  // layer slice [128]
    const float* __restrict__ hvec, int layer) {
    __shared__ u16   s_a[64 * 136];
    __shared__ u16   s_h[64 * 136];
    __shared__ float s_deg[64];
    __shared__ float s_bv[128], s_b1[128], s_b2v[128];

    const int t  = threadIdx.x;
    const int n0 = blockIdx.x * 64;

    for (int i = t; i < 64 * 16; i += 256) {
        int r = i >> 4, ch = i & 15;
        int n = n0 + r;
        u16x8 v;
        if (n < N_) {
            const float4* p = (const float4*)&y[(size_t)n * L_ + ch * 8];
            float4 f0 = p[0], f1 = p[1];
            v[0] = f2bf(f0.x); v[1] = f2bf(f0.y); v[2] = f2bf(f0.z); v[3] = f2bf(f0.w);
            v[4] = f2bf(f1.x); v[5] = f2bf(f1.y); v[6] = f2bf(f1.z); v[7] = f2bf(f1.w);
        } else {
#pragma unroll
            for (int j = 0; j < 8; ++j) v[j] = 0;
        }
        *(u16x8*)&s_a[r * 136 + ch * 8] = v;
    }
    if (t < 128) { s_bv[t] = bvec[t]; s_b1[t] = nb1[t]; s_b2v[t] = nb2[t]; }
    else if (t < 192) {
        int r = t - 128, n = n0 + r;
        s_deg[r] = (n < N_) ? (float)(rowptr[n + 1] - rowptr[n]) : 0.f;
    }
    __syncthreads();

    const int l  = t & 63, w = t >> 6;
    const int r0 = w * 16;
    const int lr = l & 15, lk = l >> 4;

    bf16x8 ay[4], ah[4];
    const int nfr = n0 + r0 + lr;
#pragma unroll
    for (int ks = 0; ks < 4; ++ks) {
        ay[ks] = *(const bf16x8*)&s_a[(r0 + lr) * 136 + ks * 32 + lk * 8];
        ah[ks] = *(const bf16x8*)&Hsum[(size_t)nfr * 128 + ks * 32 + lk * 8]; // NPAD rows: safe
    }

    // GEMM1 + silu -> s_h
#pragma unroll
    for (int ct = 0; ct < 8; ++ct) {
        int c = ct * 16 + lr;
        f32x4 acc;
#pragma unroll
        for (int i = 0; i < 4; ++i)
            acc[i] = s_b1[c] + s_deg[r0 + lk * 4 + i] * s_bv[c];
#pragma unroll
        for (int ks = 0; ks < 4; ++ks) {
            bf16x8 b1f = *(const bf16x8*)&nw1at[(size_t)c * 128 + ks * 32 + lk * 8];
            acc = __builtin_amdgcn_mfma_f32_16x16x32_bf16(ay[ks], b1f, acc, 0, 0, 0);
        }
#pragma unroll
        for (int ks = 0; ks < 4; ++ks) {
            bf16x8 b2f = *(const bf16x8*)&W2nt[(size_t)c * 128 + ks * 32 + lk * 8];
            acc = __builtin_amdgcn_mfma_f32_16x16x32_bf16(ah[ks], b2f, acc, 0, 0, 0);
        }
#pragma unroll
        for (int i = 0; i < 4; ++i)
            s_h[(r0 + lk * 4 + i) * 136 + c] = f2bf(silu(acc[i]));
    }
    __syncthreads();

    bf16x8 a2[4];
#pragma unroll
    for (int ks = 0; ks < 4; ++ks)
        a2[ks] = *(const bf16x8*)&s_h[(r0 + lr) * 136 + ks * 32 + lk * 8];

    float hh = hvec[layer];
    float h2 = hh * hh;

    // GEMM2 + Verlet update
#pragma unroll
    for (int ct = 0; ct < 8; ++ct) {
        int c = ct * 16 + lr;
        float bb = s_b2v[c];
        f32x4 acc = {bb, bb, bb, bb};
#pragma unroll
        for (int ks = 0; ks < 4; ++ks) {
            bf16x8 b = *(const bf16x8*)&nw2t[(size_t)c * 128 + ks * 32 + lk * 8];
            acc = __builtin_amdgcn_mfma_f32_16x16x32_bf16(a2[ks], b, acc, 0, 0, 0);
        }
#pragma unroll
        for (int i = 0; i < 4; ++i) {
            int n = n0 + r0 + lk * 4 + i;
            if (n < N_) {
                size_t idx = (size_t)n * L_ + c;
                float yv = y[idx], yo = y_old[idx];
                y_old[idx] = yv;
                y[idx] = 2.f * yv - yo - h2 * acc[i];
            }
        }
    }
}

// ---------------- host launch ----------------

#define ALLOC(ptr, T, count) T* ptr = (T*)base; base += (((size_t)(count) * sizeof(T)) + 255) / 256 * 256;

extern "C" void kernel_launch(void* const* d_in, const int* in_sizes, int n_in,
                              void* d_out, int out_size, void* d_ws, size_t ws_size,
                              hipStream_t stream) {
    const float* x_in      = (const float*)d_in[0];
    const int*   node_attr = (const int*)  d_in[2];
    const int*   esrc      = (const int*)  d_in[3];
    const int*   edst      = (const int*)  d_in[4];
    const float* W         = (const float*)d_in[5];
    const float* embed     = (const float*)d_in[6];
    const float* hvec      = (const float*)d_in[7];
    const float* mw1       = (const float*)d_in[8];
    const float* mb1       = (const float*)d_in[9];
    const float* mw2       = (const float*)d_in[10];
    const float* mb2       = (const float*)d_in[11];
    const float* nw1       = (const float*)d_in[12];
    const float* nb1       = (const float*)d_in[13];
    const float* nw2       = (const float*)d_in[14];
    const float* nb2       = (const float*)d_in[15];
    float* out = (float*)d_out;

    char* base = (char*)d_ws;
    ALLOC(y,       float, (size_t)N_ * L_);
    ALLOC(y_old,   float, (size_t)N_ * L_);
    ALLOC(x_cur,   float, (size_t)N_ * DIM_IN_);
    ALLOC(attr_e,  float, (size_t)N_ * A_);
    ALLOC(P,       u16,   (size_t)N_ * 256);
    ALLOC(Hsum,    u16,   (size_t)NPAD_ * 128);
    ALLOC(w_csr,   float, E_);
    ALLOC(csr_src, int,   E_);
    ALLOC(perm,    int,   E_);
    ALLOC(deg,     int,   N_);
    ALLOC(rowptr,  int,   N_ + 1);
    ALLOC(cursor,  int,   N_);
    ALLOC(w1cat_t, u16,   (size_t)NL_ * 256 * 128);
    ALLOC(nw1at,   u16,   (size_t)NL_ * 128 * 128);
    ALLOC(nw2t,    u16,   (size_t)NL_ * 128 * 128);
    ALLOC(W2nt,    u16,   (size_t)NL_ * 128 * 128);
    ALLOC(w1attr,  float, (size_t)NL_ * 8 * 256);
    ALLOC(bcat,    float, (size_t)NL_ * 256);
    ALLOC(wr272,   float, (size_t)NL_ * 128);
    ALLOC(bvec,    float, (size_t)NL_ * 128);

    // weight prep + CSR build (static across layers)
    hipMemsetAsync(deg, 0, (size_t)N_ * sizeof(int), stream);
    k_prep<<<(PREP_TOTAL + 255) / 256, 256, 0, stream>>>(
        mw1, mb1, nw1, nw2, w1cat_t, nw1at, nw2t, w1attr, bcat, wr272);
    k_prep2<<<(PREP2_TOTAL + 255) / 256, 256, 0, stream>>>(mw2, mb2, nw1, W2nt, bvec);
    k_init_y<<<(N_ * L_ + 255) / 256, 256, 0, stream>>>(x_in, W, y, y_old);
    k_attr<<<(N_ * A_ + 255) / 256, 256, 0, stream>>>(node_attr, embed, attr_e);
    k_hist<<<(E_ + 255) / 256, 256, 0, stream>>>(edst, deg);
    k_scan<<<1, 1024, 0, stream>>>(deg, rowptr, cursor);
    k_fill<<<(E_ + 255) / 256, 256, 0, stream>>>(esrc, edst, cursor, perm, csr_src);

    for (int i = 0; i < NL_; ++i) {
        const float* xp = (i == 0) ? x_in : x_cur;
        if (i > 0)
            k_x<<<(N_ * DIM_IN_ + 255) / 256, 256, 0, stream>>>(y, W, x_cur);
        k_edge_w<<<(E_ + 255) / 256, 256, 0, stream>>>(xp, esrc, edst, perm, w_csr);
        k_pre<<<dim3(313, 2), 256, 0, stream>>>(
            y, attr_e,
            w1cat_t + (size_t)i * 256 * 128,
            w1attr + (size_t)i * 8 * 256,
            bcat + (size_t)i * 256,
            P);
        k_agg<<<N_ / 4, 256, 0, stream>>>(
            P, w_csr, csr_src, rowptr,
            wr272 + (size_t)i * 128,
            Hsum);
        k_node<<<313, 256, 0, stream>>>(
            y, y_old, Hsum, rowptr,
            nw1at + (size_t)i * 128 * 128,
            W2nt + (size_t)i * 128 * 128,
            nw2t + (size_t)i * 128 * 128,
            bvec + (size_t)i * 128,
            nb1 + (size_t)i * L_,
            nb2 + (size_t)i * L_,
            hvec, i);
    }

    k_x<<<(N_ * DIM_IN_ + 255) / 256, 256, 0, stream>>>(y, W, out);
    k_scalars<<<1, 4, 0, stream>>>(out + (size_t)N_ * DIM_IN_);
}

// Round 10
// 495.801 us; speedup vs baseline: 3.3019x; 1.0539x over previous
//
#include <hip/hip_runtime.h>
#include <hip/hip_bf16.h>
#include <math.h>

// Problem constants (from reference)
#define N_ 20000
#define NPAD_ 20032       // 313*64, padded row count for fragment loads
#define E_ 160000
#define DIM_IN_ 6
#define L_ 128
#define A_ 8
#define NL_ 4
#define EIN_ 273          // 2*L + 2*A + 1
#define MAX_R_ 50.0f

typedef unsigned short u16;
typedef short bf16x8 __attribute__((ext_vector_type(8)));    // 8 bf16 in 4 VGPRs
typedef u16   u16x8  __attribute__((ext_vector_type(8)));
typedef float f32x4  __attribute__((ext_vector_type(4)));

static __device__ __forceinline__ float bf2f(u16 u) {
    return __uint_as_float(((unsigned)u) << 16);
}
static __device__ __forceinline__ u16 f2bf(float f) {       // RNE
    unsigned b = __float_as_uint(f);
    return (u16)((b + 0x7FFF + ((b >> 16) & 1)) >> 16);
}
static __device__ __forceinline__ float silu(float v) {
    return v / (1.f + __expf(-v));
}

// ---------------- setup kernels ----------------

__global__ void k_init_y(const float* __restrict__ x, const float* __restrict__ W,
                         float* __restrict__ y, float* __restrict__ y_old) {
    int tid = blockIdx.x * blockDim.x + threadIdx.x;
    if (tid >= N_ * L_) return;
    int n = tid >> 7, l = tid & 127;
    float a = 0.f;
#pragma unroll
    for (int d = 0; d < DIM_IN_; ++d) a = fmaf(x[n * DIM_IN_ + d], W[l * DIM_IN_ + d], a);
    y[tid] = a;
    y_old[tid] = a;
}

__global__ void k_attr(const int* __restrict__ node_attr, const float* __restrict__ embed,
                       float* __restrict__ attr_e) {
    int tid = blockIdx.x * blockDim.x + threadIdx.x;
    if (tid >= N_ * A_) return;
    int n = tid >> 3, a = tid & 7;
    attr_e[tid] = embed[node_attr[n] * A_ + a];
}

// pos4[n] = {x[n][0..2], 0} where x = (layer==0) ? x_in : y @ W
__global__ void k_pos(const float* __restrict__ y, const float* __restrict__ W,
                      const float* __restrict__ x_in, int layer,
                      float* __restrict__ pos4) {
    int tid = blockIdx.x * blockDim.x + threadIdx.x;
    if (tid >= N_ * 4) return;
    int n = tid >> 2, d = tid & 3;
    float v = 0.f;
    if (d < 3) {
        if (layer == 0) v = x_in[n * DIM_IN_ + d];
        else {
            for (int l = 0; l < L_; ++l) v = fmaf(y[(size_t)n * L_ + l], W[l * DIM_IN_ + d], v);
        }
    }
    pos4[tid] = v;
}

// x_out[n][d] = sum_l y[n][l] * W[l][d]   (final output only)
__global__ void k_x(const float* __restrict__ y, const float* __restrict__ W,
                    float* __restrict__ x_out) {
    int tid = blockIdx.x * blockDim.x + threadIdx.x;
    if (tid >= N_ * DIM_IN_) return;
    int n = tid / DIM_IN_, d = tid % DIM_IN_;
    float a = 0.f;
    for (int l = 0; l < L_; ++l) a = fmaf(y[(size_t)n * L_ + l], W[l * DIM_IN_ + d], a);
    x_out[tid] = a;
}

__global__ void k_scalars(float* __restrict__ tail) {
    int j = threadIdx.x;
    if (j < 4) tail[j] = (j < 2) ? -1.0f : 0.0f;
}

// ---------------- CSR build (edge list is static across layers) ----------------

__global__ void k_hist(const int* __restrict__ edst, int* __restrict__ deg) {
    int e = blockIdx.x * blockDim.x + threadIdx.x;
    if (e < E_) atomicAdd(&deg[edst[e]], 1);
}

#define SCAN_CH 20   // 1024*20 = 20480 >= N_
__global__ __launch_bounds__(1024) void k_scan(const int* __restrict__ deg,
                                               int* __restrict__ rowptr,
                                               int* __restrict__ cursor) {
    __shared__ int s[1024];
    int t = threadIdx.x;
    int base = t * SCAN_CH;
    int local[SCAN_CH];
    int sum = 0;
#pragma unroll
    for (int j = 0; j < SCAN_CH; ++j) {
        int n = base + j;
        int d = (n < N_) ? deg[n] : 0;
        local[j] = d; sum += d;
    }
    s[t] = sum;
    __syncthreads();
    for (int off = 1; off < 1024; off <<= 1) {
        int v = (t >= off) ? s[t - off] : 0;
        __syncthreads();
        s[t] += v;
        __syncthreads();
    }
    int run = t ? s[t - 1] : 0;
#pragma unroll
    for (int j = 0; j < SCAN_CH; ++j) {
        int n = base + j;
        if (n < N_) { rowptr[n] = run; cursor[n] = run; run += local[j]; }
    }
    if (t == 1023) rowptr[N_] = run;   // == E_
}

__global__ void k_fill(const int* __restrict__ esrc, const int* __restrict__ edst,
                       int* __restrict__ cursor, int* __restrict__ csr_src) {
    int e = blockIdx.x * blockDim.x + threadIdx.x;
    if (e >= E_) return;
    int p = atomicAdd(&cursor[edst[e]], 1);
    csr_src[p] = esrc[e];
}

// ---------------- weight prep (once per launch) ----------------
__global__ void k_prep(const float* __restrict__ mw1, const float* __restrict__ mb1,
                       const float* __restrict__ nw1, const float* __restrict__ nw2,
                       u16* __restrict__ w1cat_t, u16* __restrict__ nw1at,
                       u16* __restrict__ nw2t,
                       float* __restrict__ w1attr, float* __restrict__ bcat,
                       float* __restrict__ wr272) {
    int idx = blockIdx.x * 256 + threadIdx.x;
    if (idx < NL_ * 256 * 128) {
        int i = idx >> 15; int rem = idx & 32767; int cc = rem >> 7; int k = rem & 127;
        int row = (cc < 128) ? k : 128 + k;
        w1cat_t[idx] = f2bf(mw1[(size_t)i * EIN_ * L_ + row * L_ + (cc & 127)]);
        return;
    }
    idx -= NL_ * 256 * 128;
    if (idx < NL_ * 128 * 128) {
        int i = idx >> 14; int rem = idx & 16383; int c = rem >> 7; int k = rem & 127;
        nw1at[idx] = f2bf(nw1[(size_t)i * 2 * L_ * L_ + k * L_ + c]);
        return;
    }
    idx -= NL_ * 128 * 128;
    if (idx < NL_ * 128 * 128) {
        int i = idx >> 14; int rem = idx & 16383; int c = rem >> 7; int k = rem & 127;
        nw2t[idx] = f2bf(nw2[(size_t)i * L_ * L_ + k * L_ + c]);
        return;
    }
    idx -= NL_ * 128 * 128;
    if (idx < NL_ * 8 * 256) {
        int i = idx >> 11; int rem = idx & 2047; int j = rem >> 8; int cc = rem & 255;
        int row = (cc < 128) ? 256 + j : 264 + j;
        w1attr[idx] = mw1[(size_t)i * EIN_ * L_ + row * L_ + (cc & 127)];
        return;
    }
    idx -= NL_ * 8 * 256;
    if (idx < NL_ * 256) {
        int i = idx >> 8; int cc = idx & 255;
        bcat[idx] = (cc < 128) ? 0.f : mb1[i * L_ + cc - 128];
        return;
    }
    idx -= NL_ * 256;
    if (idx < NL_ * 128) {
        int i = idx >> 7; int c = idx & 127;
        wr272[idx] = mw1[(size_t)i * EIN_ * L_ + 272 * L_ + c];
    }
}
#define PREP_TOTAL (NL_*256*128 + 2*NL_*128*128 + NL_*8*256 + NL_*256 + NL_*128)

// W2nt[i][c][k] = sum_j w2[i][k][j] * nw1[i][128+j][c]   (bf16, transposed for B-frag)
// bvec[i][c]   = sum_j b2[i][j]    * nw1[i][128+j][c]   (f32)
__global__ void k_prep2(const float* __restrict__ mw2, const float* __restrict__ mb2,
                        const float* __restrict__ nw1,
                        u16* __restrict__ W2nt, float* __restrict__ bvec) {
    int idx = blockIdx.x * 256 + threadIdx.x;
    if (idx < NL_ * 128 * 128) {
        int i = idx >> 14; int rem = idx & 16383; int c = rem >> 7; int k = rem & 127;
        const float* w2row = &mw2[(size_t)i * L_ * L_ + k * L_];
        const float* nb    = &nw1[(size_t)i * 2 * L_ * L_ + 128 * L_ + c];
        float a = 0.f;
        for (int j = 0; j < 128; ++j) a = fmaf(w2row[j], nb[(size_t)j * L_], a);
        W2nt[idx] = f2bf(a);
        return;
    }
    idx -= NL_ * 128 * 128;
    if (idx < NL_ * 128) {
        int i = idx >> 7; int c = idx & 127;
        const float* b2 = &mb2[i * L_];
        const float* nb = &nw1[(size_t)i * 2 * L_ * L_ + 128 * L_ + c];
        float a = 0.f;
        for (int j = 0; j < 128; ++j) a = fmaf(b2[j], nb[(size_t)j * L_], a);
        bvec[idx] = a;
    }
}
#define PREP2_TOTAL (NL_*128*128 + NL_*128)

// ---------------- per-node projection GEMM (bf16 MFMA), both col halves ----------------
// P[n][cc] = sum_k y[n][k]*w1cat[k][cc] + sum_j attr[n][j]*w1attr[j][cc] + bcat[cc]
__global__ __launch_bounds__(256) void k_pre(
    const float* __restrict__ y, const float* __restrict__ attr_e,
    const u16* __restrict__ w1cat_t,   // layer slice [256][128]
    const float* __restrict__ w1attr,  // layer slice [8][256]
    const float* __restrict__ bcat,    // layer slice [256]
    u16* __restrict__ P) {             // [N][256]
    __shared__ u16   s_a[64 * 136];
    __shared__ float s_attr[64 * 8];
    __shared__ float s_w1a[8 * 256];
    __shared__ float s_bc[256];

    const int t  = threadIdx.x;
    const int n0 = blockIdx.x * 64;

    for (int i = t; i < 64 * 16; i += 256) {
        int r = i >> 4, ch = i & 15;
        int n = n0 + r;
        u16x8 v;
        if (n < N_) {
            const float4* p = (const float4*)&y[(size_t)n * L_ + ch * 8];
            float4 f0 = p[0], f1 = p[1];
            v[0] = f2bf(f0.x); v[1] = f2bf(f0.y); v[2] = f2bf(f0.z); v[3] = f2bf(f0.w);
            v[4] = f2bf(f1.x); v[5] = f2bf(f1.y); v[6] = f2bf(f1.z); v[7] = f2bf(f1.w);
        } else {
#pragma unroll
            for (int j = 0; j < 8; ++j) v[j] = 0;
        }
        *(u16x8*)&s_a[r * 136 + ch * 8] = v;
    }
    for (int i = t; i < 64 * 2; i += 256) {
        int r = i >> 1, half = i & 1;
        int n = n0 + r;
        float4 v = make_float4(0.f, 0.f, 0.f, 0.f);
        if (n < N_) v = *(const float4*)&attr_e[(size_t)n * A_ + half * 4];
        *(float4*)&s_attr[r * 8 + half * 4] = v;
    }
    for (int i = t; i < 8 * 256; i += 256) s_w1a[i] = w1attr[i];
    if (t < 256) s_bc[t] = bcat[t];
    __syncthreads();

    const int l  = t & 63, w = t >> 6;
    const int r0 = w * 16;
    const int lr = l & 15, lk = l >> 4;

    bf16x8 a[4];
#pragma unroll
    for (int ks = 0; ks < 4; ++ks)
        a[ks] = *(const bf16x8*)&s_a[(r0 + lr) * 136 + ks * 32 + lk * 8];

#pragma unroll
    for (int cb = 0; cb < 2; ++cb) {
#pragma unroll
        for (int ct = 0; ct < 8; ++ct) {
            int cc = cb * 128 + ct * 16 + lr;
            float bb = s_bc[cc];
            f32x4 acc = {bb, bb, bb, bb};
#pragma unroll
            for (int ks = 0; ks < 4; ++ks) {
                bf16x8 b = *(const bf16x8*)&w1cat_t[(size_t)cc * 128 + ks * 32 + lk * 8];
                acc = __builtin_amdgcn_mfma_f32_16x16x32_bf16(a[ks], b, acc, 0, 0, 0);
            }
#pragma unroll
            for (int i = 0; i < 4; ++i) {
                int r = r0 + lk * 4 + i;
                int n = n0 + r;
                if (n < N_) {
                    float v = acc[i];
#pragma unroll
                    for (int j = 0; j < 8; ++j) v = fmaf(s_attr[r * 8 + j], s_w1a[j * 256 + cc], v);
                    P[(size_t)n * 256 + cc] = f2bf(v);
                }
            }
        }
    }
}

// ---------------- CSR aggregation with fused edge weight ----------------
// Hsum[n] = sum_{e: dst=n} silu(P[src][0:128] + P[n][128:256] + w(src,n)*wr272)
// One wave per node; per 64-edge chunk, lane l prefetches (src, w) in parallel,
// inner loop shfl-broadcasts them -> single independent P-row load per edge.
__global__ __launch_bounds__(256) void k_agg(
    const u16* __restrict__ P, const float* __restrict__ pos4,
    const int* __restrict__ csr_src, const int* __restrict__ rowptr,
    const float* __restrict__ wr272,   // layer slice [128]
    u16* __restrict__ Hsum) {          // [NPAD][128]
    const int t = threadIdx.x;
    const int node = blockIdx.x * 4 + (t >> 6);   // grid = 5000 blocks exactly
    const int l = t & 63;

    const int beg = rowptr[node], end = rowptr[node + 1];
    const float wr0 = wr272[2 * l], wr1 = wr272[2 * l + 1];
    unsigned pdu = *(const unsigned*)&P[(size_t)node * 256 + 128 + 2 * l];
    const float pd0 = bf2f((u16)pdu), pd1 = bf2f((u16)(pdu >> 16));
    const float4 pn = *(const float4*)&pos4[node * 4];

    float h0 = 0.f, h1 = 0.f;
    for (int cbeg = beg; cbeg < end; cbeg += 64) {
        const int cnt = min(64, end - cbeg);
        int   srcl = 0;
        float wl   = 0.f;
        if (l < cnt) {
            srcl = csr_src[cbeg + l];
            float4 ps = *(const float4*)&pos4[srcl * 4];
            float dx = ps.x - pn.x, dy = ps.y - pn.y, dz = ps.z - pn.z;
            float len = sqrtf(dx * dx + dy * dy + dz * dz);
            float u = 2.f * (len / MAX_R_ - 1.f);
            float cv;
            if (u > 0.f)       cv = 0.f;
            else if (u < -1.f) cv = 1.f;
            else               cv = 0.5f * (1.f - cosf(3.14159265358979323846f * u));
            wl = cv / len;
        }
        for (int i = 0; i < cnt; ++i) {
            int   s = __shfl(srcl, i, 64);
            float w = __shfl(wl,   i, 64);
            unsigned psu = *(const unsigned*)&P[(size_t)s * 256 + 2 * l];
            float v0 = bf2f((u16)psu)         + pd0 + w * wr0;
            float v1 = bf2f((u16)(psu >> 16)) + pd1 + w * wr1;
            h0 += silu(v0);
            h1 += silu(v1);
        }
    }
    unsigned out = (unsigned)f2bf(h0) | ((unsigned)f2bf(h1) << 16);
    *(unsigned*)&Hsum[(size_t)node * 128 + 2 * l] = out;
}

// ---------------- node MLP (bf16 MFMA) + Verlet update ----------------
__global__ __launch_bounds__(256) void k_node(
    float* __restrict__ y, float* __restrict__ y_old,
    const u16* __restrict__ Hsum, const int* __restrict__ rowptr,
    const u16* __restrict__ nw1at,  // layer slice [128][128]
    const u16* __restrict__ W2nt,   // layer slice [128][128]
    const u16* __restrict__ nw2t,   // layer slice [128][128]
    const float* __restrict__ bvec, // layer slice [128]
    const float* __restrict__ nb1,  // layer slice [128]
    const float* __restrict__ nb2,  // layer slice [128]
    const float* __restrict__ hvec, int layer) {
    __shared__ u16   s_a[64 * 136];
    __shared__ u16   s_h[64 * 136];
    __shared__ float s_deg[64];
    __shared__ float s_bv[128], s_b1[128], s_b2v[128];

    const int t  = threadIdx.x;
    const int n0 = blockIdx.x * 64;

    for (int i = t; i < 64 * 16; i += 256) {
        int r = i >> 4, ch = i & 15;
        int n = n0 + r;
        u16x8 v;
        if (n < N_) {
            const float4* p = (const float4*)&y[(size_t)n * L_ + ch * 8];
            float4 f0 = p[0], f1 = p[1];
            v[0] = f2bf(f0.x); v[1] = f2bf(f0.y); v[2] = f2bf(f0.z); v[3] = f2bf(f0.w);
            v[4] = f2bf(f1.x); v[5] = f2bf(f1.y); v[6] = f2bf(f1.z); v[7] = f2bf(f1.w);
        } else {
#pragma unroll
            for (int j = 0; j < 8; ++j) v[j] = 0;
        }
        *(u16x8*)&s_a[r * 136 + ch * 8] = v;
    }
    if (t < 128) { s_bv[t] = bvec[t]; s_b1[t] = nb1[t]; s_b2v[t] = nb2[t]; }
    else if (t < 192) {
        int r = t - 128, n = n0 + r;
        s_deg[r] = (n < N_) ? (float)(rowptr[n + 1] - rowptr[n]) : 0.f;
    }
    __syncthreads();

    const int l  = t & 63, w = t >> 6;
    const int r0 = w * 16;
    const int lr = l & 15, lk = l >> 4;

    bf16x8 ay[4], ah[4];
    const int nfr = n0 + r0 + lr;
#pragma unroll
    for (int ks = 0; ks < 4; ++ks) {
        ay[ks] = *(const bf16x8*)&s_a[(r0 + lr) * 136 + ks * 32 + lk * 8];
        ah[ks] = *(const bf16x8*)&Hsum[(size_t)nfr * 128 + ks * 32 + lk * 8]; // NPAD rows: safe
    }

    // GEMM1 + silu -> s_h
#pragma unroll
    for (int ct = 0; ct < 8; ++ct) {
        int c = ct * 16 + lr;
        f32x4 acc;
#pragma unroll
        for (int i = 0; i < 4; ++i)
            acc[i] = s_b1[c] + s_deg[r0 + lk * 4 + i] * s_bv[c];
#pragma unroll
        for (int ks = 0; ks < 4; ++ks) {
            bf16x8 b1f = *(const bf16x8*)&nw1at[(size_t)c * 128 + ks * 32 + lk * 8];
            acc = __builtin_amdgcn_mfma_f32_16x16x32_bf16(ay[ks], b1f, acc, 0, 0, 0);
        }
#pragma unroll
        for (int ks = 0; ks < 4; ++ks) {
            bf16x8 b2f = *(const bf16x8*)&W2nt[(size_t)c * 128 + ks * 32 + lk * 8];
            acc = __builtin_amdgcn_mfma_f32_16x16x32_bf16(ah[ks], b2f, acc, 0, 0, 0);
        }
#pragma unroll
        for (int i = 0; i < 4; ++i)
            s_h[(r0 + lk * 4 + i) * 136 + c] = f2bf(silu(acc[i]));
    }
    __syncthreads();

    bf16x8 a2[4];
#pragma unroll
    for (int ks = 0; ks < 4; ++ks)
        a2[ks] = *(const bf16x8*)&s_h[(r0 + lr) * 136 + ks * 32 + lk * 8];

    float hh = hvec[layer];
    float h2 = hh * hh;

    // GEMM2 + Verlet update
#pragma unroll
    for (int ct = 0; ct < 8; ++ct) {
        int c = ct * 16 + lr;
        float bb = s_b2v[c];
        f32x4 acc = {bb, bb, bb, bb};
#pragma unroll
        for (int ks = 0; ks < 4; ++ks) {
            bf16x8 b = *(const bf16x8*)&nw2t[(size_t)c * 128 + ks * 32 + lk * 8];
            acc = __builtin_amdgcn_mfma_f32_16x16x32_bf16(a2[ks], b, acc, 0, 0, 0);
        }
#pragma unroll
        for (int i = 0; i < 4; ++i) {
            int n = n0 + r0 + lk * 4 + i;
            if (n < N_) {
                size_t idx = (size_t)n * L_ + c;
                float yv = y[idx], yo = y_old[idx];
                y_old[idx] = yv;
                y[idx] = 2.f * yv - yo - h2 * acc[i];
            }
        }
    }
}

// ---------------- host launch ----------------

#define ALLOC(ptr, T, count) T* ptr = (T*)base; base += (((size_t)(count) * sizeof(T)) + 255) / 256 * 256;

extern "C" void kernel_launch(void* const* d_in, const int* in_sizes, int n_in,
                              void* d_out, int out_size, void* d_ws, size_t ws_size,
                              hipStream_t stream) {
    const float* x_in      = (const float*)d_in[0];
    const int*   node_attr = (const int*)  d_in[2];
    const int*   esrc      = (const int*)  d_in[3];
    const int*   edst      = (const int*)  d_in[4];
    const float* W         = (const float*)d_in[5];
    const float* embed     = (const float*)d_in[6];
    const float* hvec      = (const float*)d_in[7];
    const float* mw1       = (const float*)d_in[8];
    const float* mb1       = (const float*)d_in[9];
    const float* mw2       = (const float*)d_in[10];
    const float* mb2       = (const float*)d_in[11];
    const float* nw1       = (const float*)d_in[12];
    const float* nb1       = (const float*)d_in[13];
    const float* nw2       = (const float*)d_in[14];
    const float* nb2       = (const float*)d_in[15];
    float* out = (float*)d_out;

    char* base = (char*)d_ws;
    ALLOC(y,       float, (size_t)N_ * L_);
    ALLOC(y_old,   float, (size_t)N_ * L_);
    ALLOC(attr_e,  float, (size_t)N_ * A_);
    ALLOC(pos4,    float, (size_t)N_ * 4);
    ALLOC(P,       u16,   (size_t)N_ * 256);
    ALLOC(Hsum,    u16,   (size_t)NPAD_ * 128);
    ALLOC(csr_src, int,   E_);
    ALLOC(deg,     int,   N_);
    ALLOC(rowptr,  int,   N_ + 1);
    ALLOC(cursor,  int,   N_);
    ALLOC(w1cat_t, u16,   (size_t)NL_ * 256 * 128);
    ALLOC(nw1at,   u16,   (size_t)NL_ * 128 * 128);
    ALLOC(nw2t,    u16,   (size_t)NL_ * 128 * 128);
    ALLOC(W2nt,    u16,   (size_t)NL_ * 128 * 128);
    ALLOC(w1attr,  float, (size_t)NL_ * 8 * 256);
    ALLOC(bcat,    float, (size_t)NL_ * 256);
    ALLOC(wr272,   float, (size_t)NL_ * 128);
    ALLOC(bvec,    float, (size_t)NL_ * 128);

    // weight prep + CSR build (static across layers)
    hipMemsetAsync(deg, 0, (size_t)N_ * sizeof(int), stream);
    k_prep<<<(PREP_TOTAL + 255) / 256, 256, 0, stream>>>(
        mw1, mb1, nw1, nw2, w1cat_t, nw1at, nw2t, w1attr, bcat, wr272);
    k_prep2<<<(PREP2_TOTAL + 255) / 256, 256, 0, stream>>>(mw2, mb2, nw1, W2nt, bvec);
    k_init_y<<<(N_ * L_ + 255) / 256, 256, 0, stream>>>(x_in, W, y, y_old);
    k_attr<<<(N_ * A_ + 255) / 256, 256, 0, stream>>>(node_attr, embed, attr_e);
    k_hist<<<(E_ + 255) / 256, 256, 0, stream>>>(edst, deg);
    k_scan<<<1, 1024, 0, stream>>>(deg, rowptr, cursor);
    k_fill<<<(E_ + 255) / 256, 256, 0, stream>>>(esrc, edst, cursor, csr_src);

    for (int i = 0; i < NL_; ++i) {
        k_pos<<<(N_ * 4 + 255) / 256, 256, 0, stream>>>(y, W, x_in, i, pos4);
        k_pre<<<313, 256, 0, stream>>>(
            y, attr_e,
            w1cat_t + (size_t)i * 256 * 128,
            w1attr + (size_t)i * 8 * 256,
            bcat + (size_t)i * 256,
            P);
        k_agg<<<N_ / 4, 256, 0, stream>>>(
            P, pos4, csr_src, rowptr,
            wr272 + (size_t)i * 128,
            Hsum);
        k_node<<<313, 256, 0, stream>>>(
            y, y_old, Hsum, rowptr,
            nw1at + (size_t)i * 128 * 128,
            W2nt + (size_t)i * 128 * 128,
            nw2t + (size_t)i * 128 * 128,
            bvec + (size_t)i * 128,
            nb1 + (size_t)i * L_,
            nb2 + (size_t)i * L_,
            hvec, i);
    }

    k_x<<<(N_ * DIM_IN_ + 255) / 256, 256, 0, stream>>>(y, W, out);
    k_scalars<<<1, 4, 0, stream>>>(out + (size_t)N_ * DIM_IN_);
}

// Round 12
// 469.566 us; speedup vs baseline: 3.4863x; 1.0559x over previous
//
#include <hip/hip_runtime.h>
#include <hip/hip_bf16.h>
#include <math.h>

// Problem constants (from reference)
#define N_ 20000
#define NPAD_ 20032       // 313*64, padded row count for fragment loads
#define E_ 160000
#define DIM_IN_ 6
#define L_ 128
#define A_ 8
#define NL_ 4
#define EIN_ 273          // 2*L + 2*A + 1
#define MAX_R_ 50.0f

typedef unsigned short u16;
typedef short bf16x8 __attribute__((ext_vector_type(8)));    // 8 bf16 in 4 VGPRs
typedef u16   u16x8  __attribute__((ext_vector_type(8)));
typedef float f32x4  __attribute__((ext_vector_type(4)));

static __device__ __forceinline__ float bf2f(u16 u) {
    return __uint_as_float(((unsigned)u) << 16);
}
static __device__ __forceinline__ u16 f2bf(float f) {       // RNE
    unsigned b = __float_as_uint(f);
    return (u16)((b + 0x7FFF + ((b >> 16) & 1)) >> 16);
}
static __device__ __forceinline__ float silu(float v) {
    return v / (1.f + __expf(-v));
}

// ---------------- setup kernels ----------------

// y0 = x @ W^T (f32); also pos4 for layer 0 from x_in
__global__ void k_init_y(const float* __restrict__ x, const float* __restrict__ W,
                         float* __restrict__ y, float* __restrict__ y_old,
                         float* __restrict__ pos4) {
    int tid = blockIdx.x * blockDim.x + threadIdx.x;
    if (tid < N_ * 4) {
        int n = tid >> 2, d = tid & 3;
        pos4[tid] = (d < 3) ? x[n * DIM_IN_ + d] : 0.f;
    }
    if (tid >= N_ * L_) return;
    int n = tid >> 7, l = tid & 127;
    float a = 0.f;
#pragma unroll
    for (int d = 0; d < DIM_IN_; ++d) a = fmaf(x[n * DIM_IN_ + d], W[l * DIM_IN_ + d], a);
    y[tid] = a;
    y_old[tid] = a;
}

__global__ void k_attr(const int* __restrict__ node_attr, const float* __restrict__ embed,
                       float* __restrict__ attr_e) {
    int tid = blockIdx.x * blockDim.x + threadIdx.x;
    if (tid >= N_ * A_) return;
    int n = tid >> 3, a = tid & 7;
    attr_e[tid] = embed[node_attr[n] * A_ + a];
}

// x_out[n][d] = sum_l y[n][l] * W[l][d]   (final output only)
__global__ void k_x(const float* __restrict__ y, const float* __restrict__ W,
                    float* __restrict__ x_out) {
    int tid = blockIdx.x * blockDim.x + threadIdx.x;
    if (tid >= N_ * DIM_IN_) return;
    int n = tid / DIM_IN_, d = tid % DIM_IN_;
    float a = 0.f;
    for (int l = 0; l < L_; ++l) a = fmaf(y[(size_t)n * L_ + l], W[l * DIM_IN_ + d], a);
    x_out[tid] = a;
}

__global__ void k_scalars(float* __restrict__ tail) {
    int j = threadIdx.x;
    if (j < 4) tail[j] = (j < 2) ? -1.0f : 0.0f;
}

// ---------------- CSR build (edge list is static across layers) ----------------

__global__ void k_hist(const int* __restrict__ edst, int* __restrict__ deg) {
    int e = blockIdx.x * blockDim.x + threadIdx.x;
    if (e < E_) atomicAdd(&deg[edst[e]], 1);
}

#define SCAN_CH 20   // 1024*20 = 20480 >= N_
__global__ __launch_bounds__(1024) void k_scan(const int* __restrict__ deg,
                                               int* __restrict__ rowptr,
                                               int* __restrict__ cursor) {
    __shared__ int s[1024];
    int t = threadIdx.x;
    int base = t * SCAN_CH;
    int local[SCAN_CH];
    int sum = 0;
#pragma unroll
    for (int j = 0; j < SCAN_CH; ++j) {
        int n = base + j;
        int d = (n < N_) ? deg[n] : 0;
        local[j] = d; sum += d;
    }
    s[t] = sum;
    __syncthreads();
    for (int off = 1; off < 1024; off <<= 1) {
        int v = (t >= off) ? s[t - off] : 0;
        __syncthreads();
        s[t] += v;
        __syncthreads();
    }
    int run = t ? s[t - 1] : 0;
#pragma unroll
    for (int j = 0; j < SCAN_CH; ++j) {
        int n = base + j;
        if (n < N_) { rowptr[n] = run; cursor[n] = run; run += local[j]; }
    }
    if (t == 1023) rowptr[N_] = run;   // == E_
}

__global__ void k_fill(const int* __restrict__ esrc, const int* __restrict__ edst,
                       int* __restrict__ cursor, int* __restrict__ csr_src) {
    int e = blockIdx.x * blockDim.x + threadIdx.x;
    if (e >= E_) return;
    int p = atomicAdd(&cursor[edst[e]], 1);
    csr_src[p] = esrc[e];
}

// ---------------- weight prep (once per launch) ----------------
__global__ void k_prep(const float* __restrict__ mw1, const float* __restrict__ mb1,
                       const float* __restrict__ nw1, const float* __restrict__ nw2,
                       u16* __restrict__ w1cat_t, u16* __restrict__ nw1at,
                       u16* __restrict__ nw2t,
                       float* __restrict__ w1attr, float* __restrict__ bcat,
                       float* __restrict__ wr272) {
    int idx = blockIdx.x * 256 + threadIdx.x;
    if (idx < NL_ * 256 * 128) {
        int i = idx >> 15; int rem = idx & 32767; int cc = rem >> 7; int k = rem & 127;
        int row = (cc < 128) ? k : 128 + k;
        w1cat_t[idx] = f2bf(mw1[(size_t)i * EIN_ * L_ + row * L_ + (cc & 127)]);
        return;
    }
    idx -= NL_ * 256 * 128;
    if (idx < NL_ * 128 * 128) {
        int i = idx >> 14; int rem = idx & 16383; int c = rem >> 7; int k = rem & 127;
        nw1at[idx] = f2bf(nw1[(size_t)i * 2 * L_ * L_ + k * L_ + c]);
        return;
    }
    idx -= NL_ * 128 * 128;
    if (idx < NL_ * 128 * 128) {
        int i = idx >> 14; int rem = idx & 16383; int c = rem >> 7; int k = rem & 127;
        nw2t[idx] = f2bf(nw2[(size_t)i * L_ * L_ + k * L_ + c]);
        return;
    }
    idx -= NL_ * 128 * 128;
    if (idx < NL_ * 8 * 256) {
        int i = idx >> 11; int rem = idx & 2047; int j = rem >> 8; int cc = rem & 255;
        int row = (cc < 128) ? 256 + j : 264 + j;
        w1attr[idx] = mw1[(size_t)i * EIN_ * L_ + row * L_ + (cc & 127)];
        return;
    }
    idx -= NL_ * 8 * 256;
    if (idx < NL_ * 256) {
        int i = idx >> 8; int cc = idx & 255;
        bcat[idx] = (cc < 128) ? 0.f : mb1[i * L_ + cc - 128];
        return;
    }
    idx -= NL_ * 256;
    if (idx < NL_ * 128) {
        int i = idx >> 7; int c = idx & 127;
        wr272[idx] = mw1[(size_t)i * EIN_ * L_ + 272 * L_ + c];
    }
}
#define PREP_TOTAL (NL_*256*128 + 2*NL_*128*128 + NL_*8*256 + NL_*256 + NL_*128)

// W2nt[i][c][k] = sum_j w2[i][k][j] * nw1[i][128+j][c]   (bf16, transposed for B-frag)
// bvec[i][c]   = sum_j b2[i][j]    * nw1[i][128+j][c]   (f32)
__global__ void k_prep2(const float* __restrict__ mw2, const float* __restrict__ mb2,
                        const float* __restrict__ nw1,
                        u16* __restrict__ W2nt, float* __restrict__ bvec) {
    int idx = blockIdx.x * 256 + threadIdx.x;
    if (idx < NL_ * 128 * 128) {
        int i = idx >> 14; int rem = idx & 16383; int c = rem >> 7; int k = rem & 127;
        const float* w2row = &mw2[(size_t)i * L_ * L_ + k * L_];
        const float* nb    = &nw1[(size_t)i * 2 * L_ * L_ + 128 * L_ + c];
        float a = 0.f;
        for (int j = 0; j < 128; ++j) a = fmaf(w2row[j], nb[(size_t)j * L_], a);
        W2nt[idx] = f2bf(a);
        return;
    }
    idx -= NL_ * 128 * 128;
    if (idx < NL_ * 128) {
        int i = idx >> 7; int c = idx & 127;
        const float* b2 = &mb2[i * L_];
        const float* nb = &nw1[(size_t)i * 2 * L_ * L_ + 128 * L_ + c];
        float a = 0.f;
        for (int j = 0; j < 128; ++j) a = fmaf(b2[j], nb[(size_t)j * L_], a);
        bvec[idx] = a;
    }
}
#define PREP2_TOTAL (NL_*128*128 + NL_*128)

// ---------------- per-node projection GEMM (bf16 MFMA) — layer 0 only ----------------
// P[n][cc] = sum_k y[n][k]*w1cat[k][cc] + sum_j attr[n][j]*w1attr[j][cc] + bcat[cc]
__global__ __launch_bounds__(256) void k_pre(
    const float* __restrict__ y, const float* __restrict__ attr_e,
    const u16* __restrict__ w1cat_t,   // layer slice [256][128]
    const float* __restrict__ w1attr,  // layer slice [8][256]
    const float* __restrict__ bcat,    // layer slice [256]
    u16* __restrict__ P) {             // [N][256]
    __shared__ u16   s_a[64 * 136];
    __shared__ float s_attr[64 * 8];
    __shared__ float s_w1a[8 * 256];
    __shared__ float s_bc[256];

    const int t  = threadIdx.x;
    const int n0 = blockIdx.x * 64;

    for (int i = t; i < 64 * 16; i += 256) {
        int r = i >> 4, ch = i & 15;
        int n = n0 + r;
        u16x8 v;
        if (n < N_) {
            const float4* p = (const float4*)&y[(size_t)n * L_ + ch * 8];
            float4 f0 = p[0], f1 = p[1];
            v[0] = f2bf(f0.x); v[1] = f2bf(f0.y); v[2] = f2bf(f0.z); v[3] = f2bf(f0.w);
            v[4] = f2bf(f1.x); v[5] = f2bf(f1.y); v[6] = f2bf(f1.z); v[7] = f2bf(f1.w);
        } else {
#pragma unroll
            for (int j = 0; j < 8; ++j) v[j] = 0;
        }
        *(u16x8*)&s_a[r * 136 + ch * 8] = v;
    }
    for (int i = t; i < 64 * 2; i += 256) {
        int r = i >> 1, half = i & 1;
        int n = n0 + r;
        float4 v = make_float4(0.f, 0.f, 0.f, 0.f);
        if (n < N_) v = *(const float4*)&attr_e[(size_t)n * A_ + half * 4];
        *(float4*)&s_attr[r * 8 + half * 4] = v;
    }
    for (int i = t; i < 8 * 256; i += 256) s_w1a[i] = w1attr[i];
    if (t < 256) s_bc[t] = bcat[t];
    __syncthreads();

    const int l  = t & 63, w = t >> 6;
    const int r0 = w * 16;
    const int lr = l & 15, lk = l >> 4;

    bf16x8 a[4];
#pragma unroll
    for (int ks = 0; ks < 4; ++ks)
        a[ks] = *(const bf16x8*)&s_a[(r0 + lr) * 136 + ks * 32 + lk * 8];

#pragma unroll
    for (int cb = 0; cb < 2; ++cb) {
#pragma unroll
        for (int ct = 0; ct < 8; ++ct) {
            int cc = cb * 128 + ct * 16 + lr;
            float bb = s_bc[cc];
            f32x4 acc = {bb, bb, bb, bb};
#pragma unroll
            for (int ks = 0; ks < 4; ++ks) {
                bf16x8 b = *(const bf16x8*)&w1cat_t[(size_t)cc * 128 + ks * 32 + lk * 8];
                acc = __builtin_amdgcn_mfma_f32_16x16x32_bf16(a[ks], b, acc, 0, 0, 0);
            }
#pragma unroll
            for (int i = 0; i < 4; ++i) {
                int r = r0 + lk * 4 + i;
                int n = n0 + r;
                if (n < N_) {
                    float v = acc[i];
#pragma unroll
                    for (int j = 0; j < 8; ++j) v = fmaf(s_attr[r * 8 + j], s_w1a[j * 256 + cc], v);
                    P[(size_t)n * 256 + cc] = f2bf(v);
                }
            }
        }
    }
}

// ---------------- CSR aggregation with fused edge weight ----------------
__global__ __launch_bounds__(256) void k_agg(
    const u16* __restrict__ P, const float* __restrict__ pos4,
    const int* __restrict__ csr_src, const int* __restrict__ rowptr,
    const float* __restrict__ wr272,   // layer slice [128]
    u16* __restrict__ Hsum) {          // [NPAD][128]
    const int t = threadIdx.x;
    const int node = blockIdx.x * 4 + (t >> 6);   // grid = 5000 blocks exactly
    const int l = t & 63;

    const int beg = rowptr[node], end = rowptr[node + 1];
    const float wr0 = wr272[2 * l], wr1 = wr272[2 * l + 1];
    unsigned pdu = *(const unsigned*)&P[(size_t)node * 256 + 128 + 2 * l];
    const float pd0 = bf2f((u16)pdu), pd1 = bf2f((u16)(pdu >> 16));
    const float4 pn = *(const float4*)&pos4[node * 4];

    float h0 = 0.f, h1 = 0.f;
    for (int cbeg = beg; cbeg < end; cbeg += 64) {
        const int cnt = min(64, end - cbeg);
        int   srcl = 0;
        float wl   = 0.f;
        if (l < cnt) {
            srcl = csr_src[cbeg + l];
            float4 ps = *(const float4*)&pos4[srcl * 4];
            float dx = ps.x - pn.x, dy = ps.y - pn.y, dz = ps.z - pn.z;
            float len = sqrtf(dx * dx + dy * dy + dz * dz);
            float u = 2.f * (len / MAX_R_ - 1.f);
            float cv;
            if (u > 0.f)       cv = 0.f;
            else if (u < -1.f) cv = 1.f;
            else               cv = 0.5f * (1.f - cosf(3.14159265358979323846f * u));
            wl = cv / len;
        }
        for (int i = 0; i < cnt; ++i) {
            int   s = __shfl(srcl, i, 64);
            float w = __shfl(wl,   i, 64);
            unsigned psu = *(const unsigned*)&P[(size_t)s * 256 + 2 * l];
            float v0 = bf2f((u16)psu)         + pd0 + w * wr0;
            float v1 = bf2f((u16)(psu >> 16)) + pd1 + w * wr1;
            h0 += silu(v0);
            h1 += silu(v1);
        }
    }
    unsigned out = (unsigned)f2bf(h0) | ((unsigned)f2bf(h1) << 16);
    *(unsigned*)&Hsum[(size_t)node * 128 + 2 * l] = out;
}

// ---------------- node MLP (bf16 MFMA) + Verlet + fused next-layer pos & P ----------------
__global__ __launch_bounds__(256) void k_node(
    float* __restrict__ y, float* __restrict__ y_old,
    const u16* __restrict__ Hsum, const int* __restrict__ rowptr,
    const u16* __restrict__ nw1at,  // layer slice [128][128]
    const u16* __restrict__ W2nt,   // layer slice [128][128]
    const u16* __restrict__ nw2t,   // layer slice [128][128]
    const float* __restrict__ bvec, // layer slice [128]
    const float* __restrict__ nb1,  // layer slice [128]
    const float* __restrict__ nb2,  // layer slice [128]
    const float* __restrict__ hvec, int layer,
    int do_next,                        // 1 for layers 0..2
    const float* __restrict__ Wmat,     // [128][6]
    const float* __restrict__ attr_e,   // [N][8]
    const u16* __restrict__ w1cat_n,    // next-layer slice [256][128]
    const float* __restrict__ w1attr_n, // next-layer slice [8][256]
    const float* __restrict__ bcat_n,   // next-layer slice [256]
    float* __restrict__ pos4, u16* __restrict__ P) {
    __shared__ u16   s_a[64 * 136];     // y bf16 in; later: new-y bf16
    __shared__ u16   s_h[64 * 136];
    __shared__ float s_deg[64];
    __shared__ float s_bv[128], s_b1[128], s_b2v[128];
    __shared__ float s_attr[64 * 8];
    __shared__ float s_w1a[8 * 256];
    __shared__ float s_bc[256];
    __shared__ float s_W[128 * 3];

    const int t  = threadIdx.x;
    const int n0 = blockIdx.x * 64;

    for (int i = t; i < 64 * 16; i += 256) {
        int r = i >> 4, ch = i & 15;
        int n = n0 + r;
        u16x8 v;
        if (n < N_) {
            const float4* p = (const float4*)&y[(size_t)n * L_ + ch * 8];
            float4 f0 = p[0], f1 = p[1];
            v[0] = f2bf(f0.x); v[1] = f2bf(f0.y); v[2] = f2bf(f0.z); v[3] = f2bf(f0.w);
            v[4] = f2bf(f1.x); v[5] = f2bf(f1.y); v[6] = f2bf(f1.z); v[7] = f2bf(f1.w);
        } else {
#pragma unroll
            for (int j = 0; j < 8; ++j) v[j] = 0;
        }
        *(u16x8*)&s_a[r * 136 + ch * 8] = v;
    }
    // next-layer staging (cheap; loaded unconditionally)
    for (int i = t; i < 64 * 2; i += 256) {
        int r = i >> 1, half = i & 1;
        int n = n0 + r;
        float4 v = make_float4(0.f, 0.f, 0.f, 0.f);
        if (n < N_) v = *(const float4*)&attr_e[(size_t)n * A_ + half * 4];
        *(float4*)&s_attr[r * 8 + half * 4] = v;
    }
    for (int i = t; i < 8 * 256; i += 256) s_w1a[i] = w1attr_n[i];
    if (t < 256) s_bc[t] = bcat_n[t];
    if (t < 128) {
        s_bv[t] = bvec[t]; s_b1[t] = nb1[t]; s_b2v[t] = nb2[t];
        s_W[t * 3 + 0] = Wmat[t * 6 + 0];
        s_W[t * 3 + 1] = Wmat[t * 6 + 1];
        s_W[t * 3 + 2] = Wmat[t * 6 + 2];
    } else if (t < 192) {
        int r = t - 128, n = n0 + r;
        s_deg[r] = (n < N_) ? (float)(rowptr[n + 1] - rowptr[n]) : 0.f;
    }
    __syncthreads();

    const int l  = t & 63, w = t >> 6;
    const int r0 = w * 16;
    const int lr = l & 15, lk = l >> 4;

    bf16x8 ay[4], ah[4];
    const int nfr = n0 + r0 + lr;
#pragma unroll
    for (int ks = 0; ks < 4; ++ks) {
        ay[ks] = *(const bf16x8*)&s_a[(r0 + lr) * 136 + ks * 32 + lk * 8];
        ah[ks] = *(const bf16x8*)&Hsum[(size_t)nfr * 128 + ks * 32 + lk * 8]; // NPAD rows: safe
    }

    // GEMM1 + silu -> s_h
#pragma unroll
    for (int ct = 0; ct < 8; ++ct) {
        int c = ct * 16 + lr;
        f32x4 acc;
#pragma unroll
        for (int i = 0; i < 4; ++i)
            acc[i] = s_b1[c] + s_deg[r0 + lk * 4 + i] * s_bv[c];
#pragma unroll
        for (int ks = 0; ks < 4; ++ks) {
            bf16x8 b1f = *(const bf16x8*)&nw1at[(size_t)c * 128 + ks * 32 + lk * 8];
            acc = __builtin_amdgcn_mfma_f32_16x16x32_bf16(ay[ks], b1f, acc, 0, 0, 0);
        }
#pragma unroll
        for (int ks = 0; ks < 4; ++ks) {
            bf16x8 b2f = *(const bf16x8*)&W2nt[(size_t)c * 128 + ks * 32 + lk * 8];
            acc = __builtin_amdgcn_mfma_f32_16x16x32_bf16(ah[ks], b2f, acc, 0, 0, 0);
        }
#pragma unroll
        for (int i = 0; i < 4; ++i)
            s_h[(r0 + lk * 4 + i) * 136 + c] = f2bf(silu(acc[i]));
    }
    __syncthreads();          // s_h complete; also: all waves past ay-loads (s_a reusable)

    bf16x8 a2[4];
#pragma unroll
    for (int ks = 0; ks < 4; ++ks)
        a2[ks] = *(const bf16x8*)&s_h[(r0 + lr) * 136 + ks * 32 + lk * 8];

    float hh = hvec[layer];
    float h2 = hh * hh;

    // GEMM2 + Verlet update; stash new y (bf16) into s_a for next-layer P
#pragma unroll
    for (int ct = 0; ct < 8; ++ct) {
        int c = ct * 16 + lr;
        float bb = s_b2v[c];
        f32x4 acc = {bb, bb, bb, bb};
#pragma unroll
        for (int ks = 0; ks < 4; ++ks) {
            bf16x8 b = *(const bf16x8*)&nw2t[(size_t)c * 128 + ks * 32 + lk * 8];
            acc = __builtin_amdgcn_mfma_f32_16x16x32_bf16(a2[ks], b, acc, 0, 0, 0);
        }
#pragma unroll
        for (int i = 0; i < 4; ++i) {
            int r = r0 + lk * 4 + i;
            int n = n0 + r;
            float ny = 0.f;
            if (n < N_) {
                size_t idx = (size_t)n * L_ + c;
                float yv = y[idx], yo = y_old[idx];
                y_old[idx] = yv;
                ny = 2.f * yv - yo - h2 * acc[i];
                y[idx] = ny;
            }
            s_a[r * 136 + c] = f2bf(ny);
        }
    }

    if (!do_next) return;
    __syncthreads();          // new y visible (global, block-fenced) + s_a complete

    // pos for next layer: identical f32 math to old k_pos (reads just-written y)
    {
        int r = t >> 2, d = t & 3;
        int n = n0 + r;
        if (n < N_) {
            float v = 0.f;
            if (d < 3)
                for (int ll = 0; ll < L_; ++ll)
                    v = fmaf(y[(size_t)n * L_ + ll], s_W[ll * 3 + d], v);
            pos4[n * 4 + d] = v;
        }
    }

    // next-layer P (identical to k_pre core; A from s_a = bf16(new y))
    bf16x8 ap[4];
#pragma unroll
    for (int ks = 0; ks < 4; ++ks)
        ap[ks] = *(const bf16x8*)&s_a[(r0 + lr) * 136 + ks * 32 + lk * 8];

#pragma unroll
    for (int cb = 0; cb < 2; ++cb) {
#pragma unroll
        for (int ct = 0; ct < 8; ++ct) {
            int cc = cb * 128 + ct * 16 + lr;
            float bb = s_bc[cc];
            f32x4 acc = {bb, bb, bb, bb};
#pragma unroll
            for (int ks = 0; ks < 4; ++ks) {
                bf16x8 b = *(const bf16x8*)&w1cat_n[(size_t)cc * 128 + ks * 32 + lk * 8];
                acc = __builtin_amdgcn_mfma_f32_16x16x32_bf16(ap[ks], b, acc, 0, 0, 0);
            }
#pragma unroll
            for (int i = 0; i < 4; ++i) {
                int r = r0 + lk * 4 + i;
                int n = n0 + r;
                if (n < N_) {
                    float v = acc[i];
#pragma unroll
                    for (int j = 0; j < 8; ++j) v = fmaf(s_attr[r * 8 + j], s_w1a[j * 256 + cc], v);
                    P[(size_t)n * 256 + cc] = f2bf(v);
                }
            }
        }
    }
}

// ---------------- host launch ----------------

#define ALLOC(ptr, T, count) T* ptr = (T*)base; base += (((size_t)(count) * sizeof(T)) + 255) / 256 * 256;

extern "C" void kernel_launch(void* const* d_in, const int* in_sizes, int n_in,
                              void* d_out, int out_size, void* d_ws, size_t ws_size,
                              hipStream_t stream) {
    const float* x_in      = (const float*)d_in[0];
    const int*   node_attr = (const int*)  d_in[2];
    const int*   esrc      = (const int*)  d_in[3];
    const int*   edst      = (const int*)  d_in[4];
    const float* W         = (const float*)d_in[5];
    const float* embed     = (const float*)d_in[6];
    const float* hvec      = (const float*)d_in[7];
    const float* mw1       = (const float*)d_in[8];
    const float* mb1       = (const float*)d_in[9];
    const float* mw2       = (const float*)d_in[10];
    const float* mb2       = (const float*)d_in[11];
    const float* nw1       = (const float*)d_in[12];
    const float* nb1       = (const float*)d_in[13];
    const float* nw2       = (const float*)d_in[14];
    const float* nb2       = (const float*)d_in[15];
    float* out = (float*)d_out;

    char* base = (char*)d_ws;
    ALLOC(y,       float, (size_t)N_ * L_);
    ALLOC(y_old,   float, (size_t)N_ * L_);
    ALLOC(attr_e,  float, (size_t)N_ * A_);
    ALLOC(pos4,    float, (size_t)N_ * 4);
    ALLOC(P,       u16,   (size_t)N_ * 256);
    ALLOC(Hsum,    u16,   (size_t)NPAD_ * 128);
    ALLOC(csr_src, int,   E_);
    ALLOC(deg,     int,   N_);
    ALLOC(rowptr,  int,   N_ + 1);
    ALLOC(cursor,  int,   N_);
    ALLOC(w1cat_t, u16,   (size_t)NL_ * 256 * 128);
    ALLOC(nw1at,   u16,   (size_t)NL_ * 128 * 128);
    ALLOC(nw2t,    u16,   (size_t)NL_ * 128 * 128);
    ALLOC(W2nt,    u16,   (size_t)NL_ * 128 * 128);
    ALLOC(w1attr,  float, (size_t)NL_ * 8 * 256);
    ALLOC(bcat,    float, (size_t)NL_ * 256);
    ALLOC(wr272,   float, (size_t)NL_ * 128);
    ALLOC(bvec,    float, (size_t)NL_ * 128);

    // weight prep + CSR build (static across layers)
    hipMemsetAsync(deg, 0, (size_t)N_ * sizeof(int), stream);
    k_prep<<<(PREP_TOTAL + 255) / 256, 256, 0, stream>>>(
        mw1, mb1, nw1, nw2, w1cat_t, nw1at, nw2t, w1attr, bcat, wr272);
    k_prep2<<<(PREP2_TOTAL + 255) / 256, 256, 0, stream>>>(mw2, mb2, nw1, W2nt, bvec);
    k_init_y<<<(N_ * L_ + 255) / 256, 256, 0, stream>>>(x_in, W, y, y_old, pos4);
    k_attr<<<(N_ * A_ + 255) / 256, 256, 0, stream>>>(node_attr, embed, attr_e);
    k_hist<<<(E_ + 255) / 256, 256, 0, stream>>>(edst, deg);
    k_scan<<<1, 1024, 0, stream>>>(deg, rowptr, cursor);
    k_fill<<<(E_ + 255) / 256, 256, 0, stream>>>(esrc, edst, cursor, csr_src);

    // P for layer 0
    k_pre<<<313, 256, 0, stream>>>(
        y, attr_e, w1cat_t, w1attr, bcat, P);

    for (int i = 0; i < NL_; ++i) {
        int nx = (i < 3) ? i + 1 : 3;    // next-layer slice (unused when do_next=0)
        k_agg<<<N_ / 4, 256, 0, stream>>>(
            P, pos4, csr_src, rowptr,
            wr272 + (size_t)i * 128,
            Hsum);
        k_node<<<313, 256, 0, stream>>>(
            y, y_old, Hsum, rowptr,
            nw1at + (size_t)i * 128 * 128,
            W2nt + (size_t)i * 128 * 128,
            nw2t + (size_t)i * 128 * 128,
            bvec + (size_t)i * 128,
            nb1 + (size_t)i * L_,
            nb2 + (size_t)i * L_,
            hvec, i,
            (i < 3) ? 1 : 0,
            W, attr_e,
            w1cat_t + (size_t)nx * 256 * 128,
            w1attr + (size_t)nx * 8 * 256,
            bcat + (size_t)nx * 256,
            pos4, P);
    }

    k_x<<<(N_ * DIM_IN_ + 255) / 256, 256, 0, stream>>>(y, W, out);
    k_scalars<<<1, 4, 0, stream>>>(out + (size_t)N_ * DIM_IN_);
}

// Round 13
// 453.503 us; speedup vs baseline: 3.6098x; 1.0354x over previous
//
#include <hip/hip_runtime.h>
#include <hip/hip_bf16.h>
#include <math.h>

// Problem constants (from reference)
#define N_ 20000
#define NPAD_ 20032       // 313*64, padded row count for fragment loads
#define E_ 160000
#define DIM_IN_ 6
#define L_ 128
#define A_ 8
#define NL_ 4
#define EIN_ 273          // 2*L + 2*A + 1
#define MAX_R_ 50.0f

typedef unsigned short u16;
typedef short bf16x8 __attribute__((ext_vector_type(8)));    // 8 bf16 in 4 VGPRs
typedef u16   u16x8  __attribute__((ext_vector_type(8)));
typedef float f32x4  __attribute__((ext_vector_type(4)));

static __device__ __forceinline__ float bf2f(u16 u) {
    return __uint_as_float(((unsigned)u) << 16);
}
static __device__ __forceinline__ u16 f2bf(float f) {       // RNE
    unsigned b = __float_as_uint(f);
    return (u16)((b + 0x7FFF + ((b >> 16) & 1)) >> 16);
}
static __device__ __forceinline__ float silu(float v) {
    return v / (1.f + __expf(-v));
}

// ---------------- setup kernels ----------------

// y0 = x @ W^T (f32); also pos4 for layer 0 from x_in
__global__ void k_init_y(const float* __restrict__ x, const float* __restrict__ W,
                         float* __restrict__ y, float* __restrict__ y_old,
                         float* __restrict__ pos4) {
    int tid = blockIdx.x * blockDim.x + threadIdx.x;
    if (tid < N_ * 4) {
        int n = tid >> 2, d = tid & 3;
        pos4[tid] = (d < 3) ? x[n * DIM_IN_ + d] : 0.f;
    }
    if (tid >= N_ * L_) return;
    int n = tid >> 7, l = tid & 127;
    float a = 0.f;
#pragma unroll
    for (int d = 0; d < DIM_IN_; ++d) a = fmaf(x[n * DIM_IN_ + d], W[l * DIM_IN_ + d], a);
    y[tid] = a;
    y_old[tid] = a;
}

__global__ void k_attr(const int* __restrict__ node_attr, const float* __restrict__ embed,
                       float* __restrict__ attr_e) {
    int tid = blockIdx.x * blockDim.x + threadIdx.x;
    if (tid >= N_ * A_) return;
    int n = tid >> 3, a = tid & 7;
    attr_e[tid] = embed[node_attr[n] * A_ + a];
}

// x_out[n][d] = sum_l y[n][l] * W[l][d]   (final output only)
__global__ void k_x(const float* __restrict__ y, const float* __restrict__ W,
                    float* __restrict__ x_out) {
    int tid = blockIdx.x * blockDim.x + threadIdx.x;
    if (tid >= N_ * DIM_IN_) return;
    int n = tid / DIM_IN_, d = tid % DIM_IN_;
    float a = 0.f;
    for (int l = 0; l < L_; ++l) a = fmaf(y[(size_t)n * L_ + l], W[l * DIM_IN_ + d], a);
    x_out[tid] = a;
}

__global__ void k_scalars(float* __restrict__ tail) {
    int j = threadIdx.x;
    if (j < 4) tail[j] = (j < 2) ? -1.0f : 0.0f;
}

// ---------------- CSR build (edge list is static across layers) ----------------

__global__ void k_hist(const int* __restrict__ edst, int* __restrict__ deg) {
    int e = blockIdx.x * blockDim.x + threadIdx.x;
    if (e < E_) atomicAdd(&deg[edst[e]], 1);
}

#define SCAN_CH 20   // 1024*20 = 20480 >= N_
__global__ __launch_bounds__(1024) void k_scan(const int* __restrict__ deg,
                                               int* __restrict__ rowptr,
                                               int* __restrict__ cursor) {
    __shared__ int s[1024];
    int t = threadIdx.x;
    int base = t * SCAN_CH;
    int local[SCAN_CH];
    int sum = 0;
#pragma unroll
    for (int j = 0; j < SCAN_CH; ++j) {
        int n = base + j;
        int d = (n < N_) ? deg[n] : 0;
        local[j] = d; sum += d;
    }
    s[t] = sum;
    __syncthreads();
    for (int off = 1; off < 1024; off <<= 1) {
        int v = (t >= off) ? s[t - off] : 0;
        __syncthreads();
        s[t] += v;
        __syncthreads();
    }
    int run = t ? s[t - 1] : 0;
#pragma unroll
    for (int j = 0; j < SCAN_CH; ++j) {
        int n = base + j;
        if (n < N_) { rowptr[n] = run; cursor[n] = run; run += local[j]; }
    }
    if (t == 1023) rowptr[N_] = run;   // == E_
}

__global__ void k_fill(const int* __restrict__ esrc, const int* __restrict__ edst,
                       int* __restrict__ cursor, int* __restrict__ csr_src) {
    int e = blockIdx.x * blockDim.x + threadIdx.x;
    if (e >= E_) return;
    int p = atomicAdd(&cursor[edst[e]], 1);
    csr_src[p] = esrc[e];
}

// ---------------- weight prep (once per launch) ----------------
__global__ void k_prep(const float* __restrict__ mw1, const float* __restrict__ mb1,
                       const float* __restrict__ nw1, const float* __restrict__ nw2,
                       u16* __restrict__ w1cat_t, u16* __restrict__ nw1at,
                       u16* __restrict__ nw2t,
                       float* __restrict__ w1attr, float* __restrict__ bcat,
                       float* __restrict__ wr272) {
    int idx = blockIdx.x * 256 + threadIdx.x;
    if (idx < NL_ * 256 * 128) {
        int i = idx >> 15; int rem = idx & 32767; int cc = rem >> 7; int k = rem & 127;
        int row = (cc < 128) ? k : 128 + k;
        w1cat_t[idx] = f2bf(mw1[(size_t)i * EIN_ * L_ + row * L_ + (cc & 127)]);
        return;
    }
    idx -= NL_ * 256 * 128;
    if (idx < NL_ * 128 * 128) {
        int i = idx >> 14; int rem = idx & 16383; int c = rem >> 7; int k = rem & 127;
        nw1at[idx] = f2bf(nw1[(size_t)i * 2 * L_ * L_ + k * L_ + c]);
        return;
    }
    idx -= NL_ * 128 * 128;
    if (idx < NL_ * 128 * 128) {
        int i = idx >> 14; int rem = idx & 16383; int c = rem >> 7; int k = rem & 127;
        nw2t[idx] = f2bf(nw2[(size_t)i * L_ * L_ + k * L_ + c]);
        return;
    }
    idx -= NL_ * 128 * 128;
    if (idx < NL_ * 8 * 256) {
        int i = idx >> 11; int rem = idx & 2047; int j = rem >> 8; int cc = rem & 255;
        int row = (cc < 128) ? 256 + j : 264 + j;
        w1attr[idx] = mw1[(size_t)i * EIN_ * L_ + row * L_ + (cc & 127)];
        return;
    }
    idx -= NL_ * 8 * 256;
    if (idx < NL_ * 256) {
        int i = idx >> 8; int cc = idx & 255;
        bcat[idx] = (cc < 128) ? 0.f : mb1[i * L_ + cc - 128];
        return;
    }
    idx -= NL_ * 256;
    if (idx < NL_ * 128) {
        int i = idx >> 7; int c = idx & 127;
        wr272[idx] = mw1[(size_t)i * EIN_ * L_ + 272 * L_ + c];
    }
}
#define PREP_TOTAL (NL_*256*128 + 2*NL_*128*128 + NL_*8*256 + NL_*256 + NL_*128)

// W2nt[i][c][k] = sum_j w2[i][k][j] * nw1[i][128+j][c]   (bf16, transposed for B-frag)
// bvec[i][c]   = sum_j b2[i][j]    * nw1[i][128+j][c]   (f32)
__global__ void k_prep2(const float* __restrict__ mw2, const float* __restrict__ mb2,
                        const float* __restrict__ nw1,
                        u16* __restrict__ W2nt, float* __restrict__ bvec) {
    int idx = blockIdx.x * 256 + threadIdx.x;
    if (idx < NL_ * 128 * 128) {
        int i = idx >> 14; int rem = idx & 16383; int c = rem >> 7; int k = rem & 127;
        const float* w2row = &mw2[(size_t)i * L_ * L_ + k * L_];
        const float* nb    = &nw1[(size_t)i * 2 * L_ * L_ + 128 * L_ + c];
        float a = 0.f;
        for (int j = 0; j < 128; ++j) a = fmaf(w2row[j], nb[(size_t)j * L_], a);
        W2nt[idx] = f2bf(a);
        return;
    }
    idx -= NL_ * 128 * 128;
    if (idx < NL_ * 128) {
        int i = idx >> 7; int c = idx & 127;
        const float* b2 = &mb2[i * L_];
        const float* nb = &nw1[(size_t)i * 2 * L_ * L_ + 128 * L_ + c];
        float a = 0.f;
        for (int j = 0; j < 128; ++j) a = fmaf(b2[j], nb[(size_t)j * L_], a);
        bvec[idx] = a;
    }
}
#define PREP2_TOTAL (NL_*128*128 + NL_*128)

// ---------------- per-node projection GEMM (bf16 MFMA) — layer 0 only ----------------
__global__ __launch_bounds__(256) void k_pre(
    const float* __restrict__ y, const float* __restrict__ attr_e,
    const u16* __restrict__ w1cat_t,   // layer slice [256][128]
    const float* __restrict__ w1attr,  // layer slice [8][256]
    const float* __restrict__ bcat,    // layer slice [256]
    u16* __restrict__ P) {             // [N][256]
    __shared__ u16   s_a[64 * 136];
    __shared__ float s_attr[64 * 8];
    __shared__ float s_w1a[8 * 256];
    __shared__ float s_bc[256];

    const int t  = threadIdx.x;
    const int n0 = blockIdx.x * 64;

    for (int i = t; i < 64 * 16; i += 256) {
        int r = i >> 4, ch = i & 15;
        int n = n0 + r;
        u16x8 v;
        if (n < N_) {
            const float4* p = (const float4*)&y[(size_t)n * L_ + ch * 8];
            float4 f0 = p[0], f1 = p[1];
            v[0] = f2bf(f0.x); v[1] = f2bf(f0.y); v[2] = f2bf(f0.z); v[3] = f2bf(f0.w);
            v[4] = f2bf(f1.x); v[5] = f2bf(f1.y); v[6] = f2bf(f1.z); v[7] = f2bf(f1.w);
        } else {
#pragma unroll
            for (int j = 0; j < 8; ++j) v[j] = 0;
        }
        *(u16x8*)&s_a[r * 136 + ch * 8] = v;
    }
    for (int i = t; i < 64 * 2; i += 256) {
        int r = i >> 1, half = i & 1;
        int n = n0 + r;
        float4 v = make_float4(0.f, 0.f, 0.f, 0.f);
        if (n < N_) v = *(const float4*)&attr_e[(size_t)n * A_ + half * 4];
        *(float4*)&s_attr[r * 8 + half * 4] = v;
    }
    for (int i = t; i < 8 * 256; i += 256) s_w1a[i] = w1attr[i];
    if (t < 256) s_bc[t] = bcat[t];
    __syncthreads();

    const int l  = t & 63, w = t >> 6;
    const int r0 = w * 16;
    const int lr = l & 15, lk = l >> 4;

    bf16x8 a[4];
#pragma unroll
    for (int ks = 0; ks < 4; ++ks)
        a[ks] = *(const bf16x8*)&s_a[(r0 + lr) * 136 + ks * 32 + lk * 8];

#pragma unroll
    for (int cb = 0; cb < 2; ++cb) {
#pragma unroll
        for (int ct = 0; ct < 8; ++ct) {
            int cc = cb * 128 + ct * 16 + lr;
            float bb = s_bc[cc];
            f32x4 acc = {bb, bb, bb, bb};
#pragma unroll
            for (int ks = 0; ks < 4; ++ks) {
                bf16x8 b = *(const bf16x8*)&w1cat_t[(size_t)cc * 128 + ks * 32 + lk * 8];
                acc = __builtin_amdgcn_mfma_f32_16x16x32_bf16(a[ks], b, acc, 0, 0, 0);
            }
#pragma unroll
            for (int i = 0; i < 4; ++i) {
                int r = r0 + lk * 4 + i;
                int n = n0 + r;
                if (n < N_) {
                    float v = acc[i];
#pragma unroll
                    for (int j = 0; j < 8; ++j) v = fmaf(s_attr[r * 8 + j], s_w1a[j * 256 + cc], v);
                    P[(size_t)n * 256 + cc] = f2bf(v);
                }
            }
        }
    }
}

// ---------------- CSR aggregation with fused edge weight ----------------
__global__ __launch_bounds__(256) void k_agg(
    const u16* __restrict__ P, const float* __restrict__ pos4,
    const int* __restrict__ csr_src, const int* __restrict__ rowptr,
    const float* __restrict__ wr272,   // layer slice [128]
    u16* __restrict__ Hsum) {          // [NPAD][128]
    const int t = threadIdx.x;
    const int node = blockIdx.x * 4 + (t >> 6);   // grid = 5000 blocks exactly
    const int l = t & 63;

    const int beg = rowptr[node], end = rowptr[node + 1];
    const float wr0 = wr272[2 * l], wr1 = wr272[2 * l + 1];
    unsigned pdu = *(const unsigned*)&P[(size_t)node * 256 + 128 + 2 * l];
    const float pd0 = bf2f((u16)pdu), pd1 = bf2f((u16)(pdu >> 16));
    const float4 pn = *(const float4*)&pos4[node * 4];

    float h0 = 0.f, h1 = 0.f;
    for (int cbeg = beg; cbeg < end; cbeg += 64) {
        const int cnt = min(64, end - cbeg);
        int   srcl = 0;
        float wl   = 0.f;
        if (l < cnt) {
            srcl = csr_src[cbeg + l];
            float4 ps = *(const float4*)&pos4[srcl * 4];
            float dx = ps.x - pn.x, dy = ps.y - pn.y, dz = ps.z - pn.z;
            float len = sqrtf(dx * dx + dy * dy + dz * dz);
            float u = 2.f * (len / MAX_R_ - 1.f);
            float cv;
            if (u > 0.f)       cv = 0.f;
            else if (u < -1.f) cv = 1.f;
            else               cv = 0.5f * (1.f - cosf(3.14159265358979323846f * u));
            wl = cv / len;
        }
        for (int i = 0; i < cnt; ++i) {
            int   s = __shfl(srcl, i, 64);
            float w = __shfl(wl,   i, 64);
            unsigned psu = *(const unsigned*)&P[(size_t)s * 256 + 2 * l];
            float v0 = bf2f((u16)psu)         + pd0 + w * wr0;
            float v1 = bf2f((u16)(psu >> 16)) + pd1 + w * wr1;
            h0 += silu(v0);
            h1 += silu(v1);
        }
    }
    unsigned out = (unsigned)f2bf(h0) | ((unsigned)f2bf(h1) << 16);
    *(unsigned*)&Hsum[(size_t)node * 128 + 2 * l] = out;
}

// ---------------- node MLP (bf16 MFMA) + Verlet + fused next-layer pos & P ----------------
// LDS-resident epilogue: coalesced y/y_old RMW; pos & P-A-fragments from LDS.
__global__ __launch_bounds__(256) void k_node(
    float* __restrict__ y, float* __restrict__ y_old,
    const u16* __restrict__ Hsum, const int* __restrict__ rowptr,
    const u16* __restrict__ nw1at,  // layer slice [128][128]
    const u16* __restrict__ W2nt,   // layer slice [128][128]
    const u16* __restrict__ nw2t,   // layer slice [128][128]
    const float* __restrict__ bvec, // layer slice [128]
    const float* __restrict__ nb1,  // layer slice [128]
    const float* __restrict__ nb2,  // layer slice [128]
    const float* __restrict__ hvec, int layer,
    int do_next,
    const float* __restrict__ Wmat,     // [128][6]
    const float* __restrict__ attr_e,   // [N][8]
    const u16* __restrict__ w1cat_n,    // next-layer slice [256][128]
    const float* __restrict__ w1attr_n, // next-layer slice [8][256]
    const float* __restrict__ bcat_n,   // next-layer slice [256]
    float* __restrict__ pos4, u16* __restrict__ P) {
    __shared__ float s_yf[64 * 132];    // f32 old-y tile (33.8 KB)
    __shared__ u16   s_h[64 * 136];     // hidden bf16 -> yn_mlp bf16 -> new-y bf16
    __shared__ float s_deg[64];
    __shared__ float s_bv[128], s_b1[128], s_b2v[128];
    __shared__ float s_attr[64 * 8];
    __shared__ float s_w1a[8 * 256];
    __shared__ float s_bc[256];
    __shared__ float s_W[128 * 3];

    const int t  = threadIdx.x;
    const int n0 = blockIdx.x * 64;

    // stage y f32 -> s_yf (zeros for OOB rows)
    for (int i = t; i < 64 * 16; i += 256) {
        int r = i >> 4, ch = i & 15;
        int n = n0 + r;
        float4 f0 = make_float4(0.f, 0.f, 0.f, 0.f), f1 = f0;
        if (n < N_) {
            const float4* p = (const float4*)&y[(size_t)n * L_ + ch * 8];
            f0 = p[0]; f1 = p[1];
        }
        *(float4*)&s_yf[r * 132 + ch * 8]     = f0;
        *(float4*)&s_yf[r * 132 + ch * 8 + 4] = f1;
    }
    for (int i = t; i < 64 * 2; i += 256) {
        int r = i >> 1, half = i & 1;
        int n = n0 + r;
        float4 v = make_float4(0.f, 0.f, 0.f, 0.f);
        if (n < N_) v = *(const float4*)&attr_e[(size_t)n * A_ + half * 4];
        *(float4*)&s_attr[r * 8 + half * 4] = v;
    }
    for (int i = t; i < 8 * 256; i += 256) s_w1a[i] = w1attr_n[i];
    if (t < 256) s_bc[t] = bcat_n[t];
    if (t < 128) {
        s_bv[t] = bvec[t]; s_b1[t] = nb1[t]; s_b2v[t] = nb2[t];
        s_W[t * 3 + 0] = Wmat[t * 6 + 0];
        s_W[t * 3 + 1] = Wmat[t * 6 + 1];
        s_W[t * 3 + 2] = Wmat[t * 6 + 2];
    } else if (t < 192) {
        int r = t - 128, n = n0 + r;
        s_deg[r] = (n < N_) ? (float)(rowptr[n + 1] - rowptr[n]) : 0.f;
    }
    __syncthreads();

    const int l  = t & 63, w = t >> 6;
    const int r0 = w * 16;
    const int lr = l & 15, lk = l >> 4;

    // A-fragments: bf16 of old y (convert from f32 LDS; bitwise = old s_a path)
    bf16x8 ay[4], ah[4];
    const int nfr = n0 + r0 + lr;
#pragma unroll
    for (int ks = 0; ks < 4; ++ks) {
        const float* src = &s_yf[(r0 + lr) * 132 + ks * 32 + lk * 8];
        bf16x8 v;
#pragma unroll
        for (int j = 0; j < 8; ++j) v[j] = (short)f2bf(src[j]);
        ay[ks] = v;
        ah[ks] = *(const bf16x8*)&Hsum[(size_t)nfr * 128 + ks * 32 + lk * 8]; // NPAD rows: safe
    }

    // GEMM1 + silu -> s_h
#pragma unroll
    for (int ct = 0; ct < 8; ++ct) {
        int c = ct * 16 + lr;
        f32x4 acc;
#pragma unroll
        for (int i = 0; i < 4; ++i)
            acc[i] = s_b1[c] + s_deg[r0 + lk * 4 + i] * s_bv[c];
#pragma unroll
        for (int ks = 0; ks < 4; ++ks) {
            bf16x8 b1f = *(const bf16x8*)&nw1at[(size_t)c * 128 + ks * 32 + lk * 8];
            acc = __builtin_amdgcn_mfma_f32_16x16x32_bf16(ay[ks], b1f, acc, 0, 0, 0);
        }
#pragma unroll
        for (int ks = 0; ks < 4; ++ks) {
            bf16x8 b2f = *(const bf16x8*)&W2nt[(size_t)c * 128 + ks * 32 + lk * 8];
            acc = __builtin_amdgcn_mfma_f32_16x16x32_bf16(ah[ks], b2f, acc, 0, 0, 0);
        }
#pragma unroll
        for (int i = 0; i < 4; ++i)
            s_h[(r0 + lk * 4 + i) * 136 + c] = f2bf(silu(acc[i]));
    }
    __syncthreads();

    bf16x8 a2[4];
#pragma unroll
    for (int ks = 0; ks < 4; ++ks)
        a2[ks] = *(const bf16x8*)&s_h[(r0 + lr) * 136 + ks * 32 + lk * 8];
    __syncthreads();   // all a2 in regs before s_h overwrite

    // GEMM2 -> yn_mlp bf16 into s_h (overwrites hidden)
#pragma unroll
    for (int ct = 0; ct < 8; ++ct) {
        int c = ct * 16 + lr;
        float bb = s_b2v[c];
        f32x4 acc = {bb, bb, bb, bb};
#pragma unroll
        for (int ks = 0; ks < 4; ++ks) {
            bf16x8 b = *(const bf16x8*)&nw2t[(size_t)c * 128 + ks * 32 + lk * 8];
            acc = __builtin_amdgcn_mfma_f32_16x16x32_bf16(a2[ks], b, acc, 0, 0, 0);
        }
#pragma unroll
        for (int i = 0; i < 4; ++i)
            s_h[(r0 + lk * 4 + i) * 136 + c] = f2bf(acc[i]);
    }
    __syncthreads();

    // Coalesced epilogue: Verlet RMW on y/y_old (float4), stash bf16(ny) into s_h
    float hh = hvec[layer];
    float h2 = hh * hh;
#pragma unroll
    for (int j = 0; j < 8; ++j) {
        int f = j * 256 + t;           // 0..2047 float4 chunks of the 64x128 tile
        int r = f >> 5, c4 = (f & 31) << 2;
        int n = n0 + r;
        if (n < N_) {
            size_t gi = (size_t)n * L_ + c4;
            float4 yold = *(const float4*)&y_old[gi];
            float4 ycur = *(const float4*)&s_yf[r * 132 + c4];
            float4 ny;
            ny.x = 2.f * ycur.x - yold.x - h2 * bf2f(s_h[r * 136 + c4 + 0]);
            ny.y = 2.f * ycur.y - yold.y - h2 * bf2f(s_h[r * 136 + c4 + 1]);
            ny.z = 2.f * ycur.z - yold.z - h2 * bf2f(s_h[r * 136 + c4 + 2]);
            ny.w = 2.f * ycur.w - yold.w - h2 * bf2f(s_h[r * 136 + c4 + 3]);
            *(float4*)&y[gi]     = ny;
            *(float4*)&y_old[gi] = ycur;
            s_h[r * 136 + c4 + 0] = f2bf(ny.x);
            s_h[r * 136 + c4 + 1] = f2bf(ny.y);
            s_h[r * 136 + c4 + 2] = f2bf(ny.z);
            s_h[r * 136 + c4 + 3] = f2bf(ny.w);
        } else {
            s_h[r * 136 + c4 + 0] = 0;
            s_h[r * 136 + c4 + 1] = 0;
            s_h[r * 136 + c4 + 2] = 0;
            s_h[r * 136 + c4 + 3] = 0;
        }
    }

    if (!do_next) return;
    __syncthreads();   // s_h = bf16(new y) complete

    // pos for next layer from bf16(new y) in LDS
    {
        int r = t >> 2, d = t & 3;
        int n = n0 + r;
        if (n < N_ && d < 3) {
            float v = 0.f;
            for (int ll = 0; ll < L_; ++ll)
                v = fmaf(bf2f(s_h[r * 136 + ll]), s_W[ll * 3 + d], v);
            pos4[n * 4 + d] = v;
        }
    }

    // next-layer P (A from s_h = bf16(new y))
    bf16x8 ap[4];
#pragma unroll
    for (int ks = 0; ks < 4; ++ks)
        ap[ks] = *(const bf16x8*)&s_h[(r0 + lr) * 136 + ks * 32 + lk * 8];

#pragma unroll
    for (int cb = 0; cb < 2; ++cb) {
#pragma unroll
        for (int ct = 0; ct < 8; ++ct) {
            int cc = cb * 128 + ct * 16 + lr;
            float bb = s_bc[cc];
            f32x4 acc = {bb, bb, bb, bb};
#pragma unroll
            for (int ks = 0; ks < 4; ++ks) {
                bf16x8 b = *(const bf16x8*)&w1cat_n[(size_t)cc * 128 + ks * 32 + lk * 8];
                acc = __builtin_amdgcn_mfma_f32_16x16x32_bf16(ap[ks], b, acc, 0, 0, 0);
            }
#pragma unroll
            for (int i = 0; i < 4; ++i) {
                int r = r0 + lk * 4 + i;
                int n = n0 + r;
                if (n < N_) {
                    float v = acc[i];
#pragma unroll
                    for (int j = 0; j < 8; ++j) v = fmaf(s_attr[r * 8 + j], s_w1a[j * 256 + cc], v);
                    P[(size_t)n * 256 + cc] = f2bf(v);
                }
            }
        }
    }
}

// ---------------- host launch ----------------

#define ALLOC(ptr, T, count) T* ptr = (T*)base; base += (((size_t)(count) * sizeof(T)) + 255) / 256 * 256;

extern "C" void kernel_launch(void* const* d_in, const int* in_sizes, int n_in,
                              void* d_out, int out_size, void* d_ws, size_t ws_size,
                              hipStream_t stream) {
    const float* x_in      = (const float*)d_in[0];
    const int*   node_attr = (const int*)  d_in[2];
    const int*   esrc      = (const int*)  d_in[3];
    const int*   edst      = (const int*)  d_in[4];
    const float* W         = (const float*)d_in[5];
    const float* embed     = (const float*)d_in[6];
    const float* hvec      = (const float*)d_in[7];
    const float* mw1       = (const float*)d_in[8];
    const float* mb1       = (const float*)d_in[9];
    const float* mw2       = (const float*)d_in[10];
    const float* mb2       = (const float*)d_in[11];
    const float* nw1       = (const float*)d_in[12];
    const float* nb1       = (const float*)d_in[13];
    const float* nw2       = (const float*)d_in[14];
    const float* nb2       = (const float*)d_in[15];
    float* out = (float*)d_out;

    char* base = (char*)d_ws;
    ALLOC(y,       float, (size_t)N_ * L_);
    ALLOC(y_old,   float, (size_t)N_ * L_);
    ALLOC(attr_e,  float, (size_t)N_ * A_);
    ALLOC(pos4,    float, (size_t)N_ * 4);
    ALLOC(P,       u16,   (size_t)N_ * 256);
    ALLOC(Hsum,    u16,   (size_t)NPAD_ * 128);
    ALLOC(csr_src, int,   E_);
    ALLOC(deg,     int,   N_);
    ALLOC(rowptr,  int,   N_ + 1);
    ALLOC(cursor,  int,   N_);
    ALLOC(w1cat_t, u16,   (size_t)NL_ * 256 * 128);
    ALLOC(nw1at,   u16,   (size_t)NL_ * 128 * 128);
    ALLOC(nw2t,    u16,   (size_t)NL_ * 128 * 128);
    ALLOC(W2nt,    u16,   (size_t)NL_ * 128 * 128);
    ALLOC(w1attr,  float, (size_t)NL_ * 8 * 256);
    ALLOC(bcat,    float, (size_t)NL_ * 256);
    ALLOC(wr272,   float, (size_t)NL_ * 128);
    ALLOC(bvec,    float, (size_t)NL_ * 128);

    // weight prep + CSR build (static across layers)
    hipMemsetAsync(deg, 0, (size_t)N_ * sizeof(int), stream);
    k_prep<<<(PREP_TOTAL + 255) / 256, 256, 0, stream>>>(
        mw1, mb1, nw1, nw2, w1cat_t, nw1at, nw2t, w1attr, bcat, wr272);
    k_prep2<<<(PREP2_TOTAL + 255) / 256, 256, 0, stream>>>(mw2, mb2, nw1, W2nt, bvec);
    k_init_y<<<(N_ * L_ + 255) / 256, 256, 0, stream>>>(x_in, W, y, y_old, pos4);
    k_attr<<<(N_ * A_ + 255) / 256, 256, 0, stream>>>(node_attr, embed, attr_e);
    k_hist<<<(E_ + 255) / 256, 256, 0, stream>>>(edst, deg);
    k_scan<<<1, 1024, 0, stream>>>(deg, rowptr, cursor);
    k_fill<<<(E_ + 255) / 256, 256, 0, stream>>>(esrc, edst, cursor, csr_src);

    // P for layer 0
    k_pre<<<313, 256, 0, stream>>>(
        y, attr_e, w1cat_t, w1attr, bcat, P);

    for (int i = 0; i < NL_; ++i) {
        int nx = (i < 3) ? i + 1 : 3;    // next-layer slice (unused when do_next=0)
        k_agg<<<N_ / 4, 256, 0, stream>>>(
            P, pos4, csr_src, rowptr,
            wr272 + (size_t)i * 128,
            Hsum);
        k_node<<<313, 256, 0, stream>>>(
            y, y_old, Hsum, rowptr,
            nw1at + (size_t)i * 128 * 128,
            W2nt + (size_t)i * 128 * 128,
            nw2t + (size_t)i * 128 * 128,
            bvec + (size_t)i * 128,
            nb1 + (size_t)i * L_,
            nb2 + (size_t)i * L_,
            hvec, i,
            (i < 3) ? 1 : 0,
            W, attr_e,
            w1cat_t + (size_t)nx * 256 * 128,
            w1attr + (size_t)nx * 8 * 256,
            bcat + (size_t)nx * 256,
            pos4, P);
    }

    k_x<<<(N_ * DIM_IN_ + 255) / 256, 256, 0, stream>>>(y, W, out);
    k_scalars<<<1, 4, 0, stream>>>(out + (size_t)N_ * DIM_IN_);
}